// Round 8
// baseline (48932.162 us; speedup 1.0000x reference)
//
#include <hip/hip_runtime.h>
#include <hip/hip_bf16.h>

#define BB 64
#define TT 32
#define VV 12000
#define EE 512
#define FF 2048
#define CDIM 128
#define HH 1024
#define LL 49
#define XHLEN 3712   /* E + F + C + H */
#define XKLEN 2688   /* E + F + C */
#define NBLK 512     /* persistent-kernel grid: 2 blocks/CU x 256 CUs */

typedef __attribute__((ext_vector_type(8))) short bf16x8;
typedef __attribute__((ext_vector_type(4))) float f32x4;

__device__ __forceinline__ unsigned short bf16_rn(float x) {
  unsigned u = __float_as_uint(x);
  u += 0x7FFFu + ((u >> 16) & 1u);
  return (unsigned short)(u >> 16);
}
__device__ __forceinline__ float bf16_tof(unsigned short h) {
  return __uint_as_float(((unsigned)h) << 16);
}
__device__ __forceinline__ void split2(float x, short& hi, short& lo) {
  unsigned short h = bf16_rn(x);
  float r = x - bf16_tof(h);
  hi = (short)h;
  lo = (short)bf16_rn(r);
}

// Device-scope grid barrier for exactly NBLK co-resident blocks.
__device__ __forceinline__ void gridbar(int* cnt, int* gen) {
  __syncthreads();
  if (threadIdx.x == 0) {
    __threadfence();   // make this block's prior global writes visible device-wide
    int g = __hip_atomic_load(gen, __ATOMIC_ACQUIRE, __HIP_MEMORY_SCOPE_AGENT);
    int v = __hip_atomic_fetch_add(cnt, 1, __ATOMIC_ACQ_REL, __HIP_MEMORY_SCOPE_AGENT);
    if (v == NBLK - 1) {
      __hip_atomic_store(cnt, 0, __ATOMIC_RELAXED, __HIP_MEMORY_SCOPE_AGENT);
      __hip_atomic_fetch_add(gen, 1, __ATOMIC_ACQ_REL, __HIP_MEMORY_SCOPE_AGENT);
    } else {
      while (__hip_atomic_load(gen, __ATOMIC_ACQUIRE, __HIP_MEMORY_SCOPE_AGENT) == g)
        __builtin_amdgcn_s_sleep(2);
    }
    __threadfence();   // agent fence: invalidate L1 so the whole CU sees fresh data
  }
  __syncthreads();
}

__global__ void zero2_k(int* p) { p[0] = 0; p[1] = 0; }

// ---------------------------------------------------------------------------
// Persistent kernel: all 32 timesteps, 4 grid barriers per step.
//  P1 (256 blk): pU[kq][b][a] partials of h @ att_U  (K split 4 ways)
//  P2 ( 64 blk): attention scores/softmax/context/emb  (sums pU inline)
//  P3 (512 blk): pG[kq][b][n] partials of [x|h] @ Wf^T (K split 8 ways)
//  P4 (256 blk): LSTM cell (sums pG + bg), writes h-split into xh and hall
// ---------------------------------------------------------------------------
__global__ __launch_bounds__(256, 2) void steps_k(
    const short* __restrict__ attUt,    // [1024][1024] bf16 = att_U^T
    const float* __restrict__ featp,    // [B*L][1024] f32
    const float* __restrict__ att_v,    // [1024]
    const float* __restrict__ features, // [B][L][F] f32
    const int*   __restrict__ captions,
    const float* __restrict__ emb,
    const short* __restrict__ Wfb,      // [4096][XHLEN] bf16
    const float* __restrict__ bg,       // [4096]
    short* __restrict__ xh_h, short* __restrict__ xh_l,  // [B][XHLEN]
    float* __restrict__ cbuf,           // [B][H]
    float* __restrict__ pU,             // [4][64][1024]
    float* __restrict__ pG,             // [8][64][4096]
    short* __restrict__ hall_h, short* __restrict__ hall_l, // [T*B][H]
    float* __restrict__ w_out,
    int* cnt, int* gen)
{
  const int gid = blockIdx.x, tid = threadIdx.x;
  const int w = tid >> 6, lane = tid & 63;
  const int r = lane & 15, kg = lane >> 4;
  __shared__ float s_w[LL];

  for (int t = 0; t < TT; ++t) {
    // ---- P1: hU partials ----
    if (gid < 256) {
      const int nt = gid >> 2, kq = gid & 3;
      const int kb = kq * 256;
      const short* wp  = attUt + (size_t)(nt * 16 + r) * HH + kb + kg * 8;
      const short* ap  = xh_h + (size_t)(w * 16 + r) * XHLEN + XKLEN + kb + kg * 8;
      const short* alp = xh_l + (size_t)(w * 16 + r) * XHLEN + XKLEN + kb + kg * 8;
      f32x4 acc = {};
#pragma unroll
      for (int k0 = 0; k0 < 256; k0 += 32) {
        bf16x8 bf = *(const bf16x8*)(wp + k0);
        bf16x8 af = *(const bf16x8*)(ap + k0);
        acc = __builtin_amdgcn_mfma_f32_16x16x32_bf16(af, bf, acc, 0, 0, 0);
        bf16x8 alf = *(const bf16x8*)(alp + k0);
        acc = __builtin_amdgcn_mfma_f32_16x16x32_bf16(alf, bf, acc, 0, 0, 0);
      }
#pragma unroll
      for (int q = 0; q < 4; ++q)
        pU[((size_t)kq * 64 + w * 16 + kg * 4 + q) * HH + nt * 16 + r] = acc[q];
    }
    gridbar(cnt, gen);

    // ---- P2: attention ----
    if (gid < BB) {
      const int b = gid;
      for (int l = w; l < LL; l += 4) {
        const float* fp = featp + ((size_t)b * LL + l) * HH;
        float acc = 0.f;
        for (int a = lane; a < HH; a += 64) {
          float hu = pU[(size_t)(0 * 64 + b) * HH + a]
                   + pU[(size_t)(1 * 64 + b) * HH + a]
                   + pU[(size_t)(2 * 64 + b) * HH + a]
                   + pU[(size_t)(3 * 64 + b) * HH + a];
          acc += tanhf(fp[a] + hu) * att_v[a];
        }
#pragma unroll
        for (int off = 32; off > 0; off >>= 1) acc += __shfl_down(acc, off);
        if (lane == 0) s_w[l] = acc;
      }
      __syncthreads();
      if (w == 0) {
        float v = (lane < LL) ? s_w[lane] : -1e30f;
        float m = v;
#pragma unroll
        for (int off = 32; off > 0; off >>= 1) m = fmaxf(m, __shfl_xor(m, off));
        float e = (lane < LL) ? expf(v - m) : 0.f;
        float s = e;
#pragma unroll
        for (int off = 32; off > 0; off >>= 1) s += __shfl_xor(s, off);
        float ww = e / s;
        if (lane < LL) {
          s_w[lane] = ww;
          w_out[((size_t)b * TT + t) * LL + lane] = ww;
        }
      }
      __syncthreads();
      for (int f = tid; f < FF; f += 256) {
        float acc = 0.f;
#pragma unroll
        for (int l = 0; l < LL; ++l)
          acc += s_w[l] * features[((size_t)b * LL + l) * FF + f];
        short hi, lo; split2(acc, hi, lo);
        xh_h[(size_t)b * XHLEN + EE + f] = hi;
        xh_l[(size_t)b * XHLEN + EE + f] = lo;
      }
      int cap = captions[b * TT + t];
      for (int j = tid; j < EE; j += 256) {
        short hi, lo; split2(emb[(size_t)cap * EE + j], hi, lo);
        xh_h[(size_t)b * XHLEN + j] = hi;
        xh_l[(size_t)b * XHLEN + j] = lo;
      }
    }
    gridbar(cnt, gen);

    // ---- P3: gates partials (all 512 blocks) ----
    {
      const int nt = gid >> 3, kq = gid & 7;       // 64 n-tiles x 8 K-chunks
      const int kiters = 14 + (kq < 4 ? 1 : 0);    // 116 = 4*15 + 4*14
      const int ks = kq * 14 + (kq < 4 ? kq : 4);  // chunk start (in 32-elem units)
      const short* ap  = xh_h + (size_t)(w * 16 + r) * XHLEN + ks * 32 + kg * 8;
      const short* alp = xh_l + (size_t)(w * 16 + r) * XHLEN + ks * 32 + kg * 8;
      const short* wr0 = Wfb + (size_t)(nt * 64 +  0 + r) * XHLEN + ks * 32 + kg * 8;
      const short* wr1 = Wfb + (size_t)(nt * 64 + 16 + r) * XHLEN + ks * 32 + kg * 8;
      const short* wr2 = Wfb + (size_t)(nt * 64 + 32 + r) * XHLEN + ks * 32 + kg * 8;
      const short* wr3 = Wfb + (size_t)(nt * 64 + 48 + r) * XHLEN + ks * 32 + kg * 8;
      f32x4 acc0 = {}, acc1 = {}, acc2 = {}, acc3 = {};
      for (int ki = 0; ki < kiters; ++ki) {
        const int k0 = ki * 32;
        bf16x8 af  = *(const bf16x8*)(ap + k0);
        bf16x8 alf = *(const bf16x8*)(alp + k0);
        bf16x8 b0 = *(const bf16x8*)(wr0 + k0);
        acc0 = __builtin_amdgcn_mfma_f32_16x16x32_bf16(af,  b0, acc0, 0, 0, 0);
        acc0 = __builtin_amdgcn_mfma_f32_16x16x32_bf16(alf, b0, acc0, 0, 0, 0);
        bf16x8 b1 = *(const bf16x8*)(wr1 + k0);
        acc1 = __builtin_amdgcn_mfma_f32_16x16x32_bf16(af,  b1, acc1, 0, 0, 0);
        acc1 = __builtin_amdgcn_mfma_f32_16x16x32_bf16(alf, b1, acc1, 0, 0, 0);
        bf16x8 b2 = *(const bf16x8*)(wr2 + k0);
        acc2 = __builtin_amdgcn_mfma_f32_16x16x32_bf16(af,  b2, acc2, 0, 0, 0);
        acc2 = __builtin_amdgcn_mfma_f32_16x16x32_bf16(alf, b2, acc2, 0, 0, 0);
        bf16x8 b3 = *(const bf16x8*)(wr3 + k0);
        acc3 = __builtin_amdgcn_mfma_f32_16x16x32_bf16(af,  b3, acc3, 0, 0, 0);
        acc3 = __builtin_amdgcn_mfma_f32_16x16x32_bf16(alf, b3, acc3, 0, 0, 0);
      }
      float* pg = pG + ((size_t)kq * 64 + w * 16 + kg * 4) * 4096 + nt * 64 + r;
#pragma unroll
      for (int q = 0; q < 4; ++q) {
        pg[(size_t)q * 4096 +  0] = acc0[q];
        pg[(size_t)q * 4096 + 16] = acc1[q];
        pg[(size_t)q * 4096 + 32] = acc2[q];
        pg[(size_t)q * 4096 + 48] = acc3[q];
      }
    }
    gridbar(cnt, gen);

    // ---- P4: LSTM + h write ----
    if (gid < 256) {
      const int idx = gid * 256 + tid;        // B*H = 65536
      const int b = idx >> 10, j = idx & 1023;
      float g4[4];
#pragma unroll
      for (int gg = 0; gg < 4; ++gg) {
        const int n = gg * 1024 + j;
        float s = bg[n];
#pragma unroll
        for (int q = 0; q < 8; ++q) s += pG[((size_t)q * 64 + b) * 4096 + n];
        g4[gg] = s;
      }
      float si = 1.f / (1.f + expf(-g4[0]));
      float sf = 1.f / (1.f + expf(-g4[1]));
      float so = 1.f / (1.f + expf(-g4[3]));
      float cc = sf * cbuf[idx] + si * tanhf(g4[2]);
      float hh = so * tanhf(cc);
      cbuf[idx] = cc;
      short hi, lo; split2(hh, hi, lo);
      xh_h[(size_t)b * XHLEN + XKLEN + j] = hi;
      xh_l[(size_t)b * XHLEN + XKLEN + j] = lo;
      const size_t ho = ((size_t)t * BB + b) * HH + j;
      hall_h[ho] = hi;
      hall_l[ho] = lo;
    }
    gridbar(cnt, gen);
  }
}

// ---------------------------------------------------------------------------
// Batched fc GEMM: Hall[T*B,H] @ fcW[V,H]^T + fc_b. Grid dim3(TT, 188):
// x-major dispatch => resident blocks cover all t for few n-tiles => W L2-hot.
// ---------------------------------------------------------------------------
__global__ __launch_bounds__(256) void bgemm_k(
    const short* __restrict__ Ah, const short* __restrict__ Al,
    const short* __restrict__ Wb, const float* __restrict__ bias,
    float* __restrict__ outs)
{
  const int tid = threadIdx.x;
  const int w = tid >> 6, l = tid & 63;
  const int r = l & 15, kg = l >> 4;
  const int t = blockIdx.x;
  const int m0 = t * 64;
  const int nrow = blockIdx.y * 64 + w * 16 + r;
  const int nc = nrow < VV ? nrow : VV - 1;
  const short* wp  = Wb + (size_t)nc * HH + kg * 8;
  const short* ap  = Ah + (size_t)(m0 + r) * HH + kg * 8;
  const short* alp = Al + (size_t)(m0 + r) * HH + kg * 8;
  f32x4 acc[4] = {};
  for (int k0 = 0; k0 < HH; k0 += 32) {
    bf16x8 bf = *(const bf16x8*)(wp + k0);
#pragma unroll
    for (int m = 0; m < 4; ++m) {
      bf16x8 af = *(const bf16x8*)(ap + (size_t)(16 * m) * HH + k0);
      acc[m] = __builtin_amdgcn_mfma_f32_16x16x32_bf16(af, bf, acc[m], 0, 0, 0);
      bf16x8 alf = *(const bf16x8*)(alp + (size_t)(16 * m) * HH + k0);
      acc[m] = __builtin_amdgcn_mfma_f32_16x16x32_bf16(alf, bf, acc[m], 0, 0, 0);
    }
  }
  if (nrow < VV) {
    float bv = bias[nrow];
#pragma unroll
    for (int m = 0; m < 4; ++m)
#pragma unroll
      for (int q = 0; q < 4; ++q) {
        int b = m * 16 + kg * 4 + q;
        outs[((size_t)b * TT + t) * VV + nrow] = acc[m][q] + bv;
      }
  }
}

// ---------------------------------------------------------------------------
// MFMA GEMM used in one-time prep (h0, c0, feat_proj).
// ---------------------------------------------------------------------------
template<bool TWOPASS, bool SPLITOUT, int MT>
__global__ __launch_bounds__(256) void mgemm_k(
    const short* __restrict__ Ah, const short* __restrict__ Al, int lda,
    const short* __restrict__ Wb, int ldw,
    const float* __restrict__ bias,
    float* __restrict__ C, int ldc,
    short* __restrict__ Ch, short* __restrict__ Cl, int ldch,
    int N, int K)
{
  const int tid = threadIdx.x;
  const int w = tid >> 6, l = tid & 63;
  const int r = l & 15, kg = l >> 4;
  const int m0 = blockIdx.y * 64;
  const int nslice = (MT == 4) ? w : (w >> 1);
  const int mbase  = (MT == 4) ? 0 : ((w & 1) * 2);
  const int n0 = blockIdx.x * (MT * 16) + nslice * 16;
  const int nrow = n0 + r;
  const int nclmp = nrow < N ? nrow : N - 1;
  const short* wp  = Wb + (size_t)nclmp * ldw + kg * 8;
  const short* ap  = Ah + (size_t)(m0 + mbase * 16 + r) * lda + kg * 8;
  const short* alp = TWOPASS ? (Al + (size_t)(m0 + mbase * 16 + r) * lda + kg * 8)
                             : nullptr;
  f32x4 acc[MT] = {};
  for (int k0 = 0; k0 < K; k0 += 32) {
    bf16x8 bf = *(const bf16x8*)(wp + k0);
#pragma unroll
    for (int m = 0; m < MT; ++m) {
      bf16x8 af = *(const bf16x8*)(ap + (size_t)(16 * m) * lda + k0);
      acc[m] = __builtin_amdgcn_mfma_f32_16x16x32_bf16(af, bf, acc[m], 0, 0, 0);
      if (TWOPASS) {
        bf16x8 alf = *(const bf16x8*)(alp + (size_t)(16 * m) * lda + k0);
        acc[m] = __builtin_amdgcn_mfma_f32_16x16x32_bf16(alf, bf, acc[m], 0, 0, 0);
      }
    }
  }
  if (nrow < N) {
    float bv = bias ? bias[nrow] : 0.f;
#pragma unroll
    for (int m = 0; m < MT; ++m) {
#pragma unroll
      for (int q = 0; q < 4; ++q) {
        int mm = m0 + (mbase + m) * 16 + kg * 4 + q;
        float v = acc[m][q] + bv;
        if (SPLITOUT) {
          short hi, lo; split2(v, hi, lo);
          Ch[(size_t)mm * ldch + nrow] = hi;
          Cl[(size_t)mm * ldch + nrow] = lo;
        } else {
          C[(size_t)mm * ldc + nrow] = v;
        }
      }
    }
  }
}

__global__ __launch_bounds__(256) void transpose_split_k(
    const float* __restrict__ in, short* __restrict__ out, int R, int C)
{
  __shared__ float tile[32][33];
  int bc = blockIdx.x * 32, br = blockIdx.y * 32;
  int tx = threadIdx.x & 31, ty4 = (threadIdx.x >> 5) << 2;
#pragma unroll
  for (int i = 0; i < 4; ++i) {
    int r = br + ty4 + i, c = bc + tx;
    tile[ty4 + i][tx] = (r < R && c < C) ? in[(size_t)r * C + c] : 0.f;
  }
  __syncthreads();
#pragma unroll
  for (int i = 0; i < 4; ++i) {
    int oc = bc + ty4 + i, orr = br + tx;
    if (oc < C && orr < R) out[(size_t)oc * R + orr] = (short)bf16_rn(tile[tx][ty4 + i]);
  }
}

__global__ __launch_bounds__(256) void cast_k(
    const float* __restrict__ in, short* __restrict__ out, size_t n)
{
  for (size_t i = blockIdx.x * 256ULL + threadIdx.x; i < n; i += gridDim.x * 256ULL)
    out[i] = (short)bf16_rn(in[i]);
}

__global__ __launch_bounds__(256) void concat_k(
    const float* __restrict__ wih, const float* __restrict__ whh,
    short* __restrict__ wf)
{
  int k = blockIdx.x * 256 + threadIdx.x;
  int n = blockIdx.y;
  if (k < XHLEN) {
    float v = (k < XKLEN) ? wih[(size_t)n * XKLEN + k]
                          : whh[(size_t)n * HH + (k - XKLEN)];
    wf[(size_t)n * XHLEN + k] = (short)bf16_rn(v);
  }
}

__global__ __launch_bounds__(256) void mean_k(
    const float* __restrict__ feat, short* __restrict__ mf)
{
  int idx = blockIdx.x * 256 + threadIdx.x;
  int b = idx >> 11, f = idx & 2047;
  float s = 0.f;
#pragma unroll
  for (int l = 0; l < LL; ++l) s += feat[((size_t)b * LL + l) * FF + f];
  mf[idx] = (short)bf16_rn(s * (1.f / 49.f));
}

__global__ __launch_bounds__(256) void setup_k(
    const float* __restrict__ b_ih, const float* __restrict__ b_hh,
    float* __restrict__ bg,
    const float* __restrict__ cat,
    short* __restrict__ xh_h, short* __restrict__ xh_l)
{
  int idx = blockIdx.x * 256 + threadIdx.x;
  if (idx < 4096) bg[idx] = b_ih[idx] + b_hh[idx];
  if (idx < BB * CDIM) {
    int b = idx >> 7, j = idx & 127;
    short hi, lo; split2(cat[idx], hi, lo);
    xh_h[(size_t)b * XHLEN + EE + FF + j] = hi;
    xh_l[(size_t)b * XHLEN + EE + FF + j] = lo;
  }
}

extern "C" void kernel_launch(void* const* d_in, const int* in_sizes, int n_in,
                              void* d_out, int out_size, void* d_ws, size_t ws_size,
                              hipStream_t stream) {
  const int*   captions = (const int*)  d_in[0];
  const float* features = (const float*)d_in[1];
  const float* category = (const float*)d_in[2];
  const float* emb      = (const float*)d_in[3];
  const float* W_ih     = (const float*)d_in[4];
  const float* b_ih     = (const float*)d_in[5];
  const float* W_hh     = (const float*)d_in[6];
  const float* b_hh     = (const float*)d_in[7];
  const float* fc_W     = (const float*)d_in[8];
  const float* fc_b     = (const float*)d_in[9];
  const float* Wh0      = (const float*)d_in[10];
  const float* bh0      = (const float*)d_in[11];
  const float* Wc0      = (const float*)d_in[12];
  const float* bc0      = (const float*)d_in[13];
  const float* att_W    = (const float*)d_in[14];
  const float* att_U    = (const float*)d_in[15];
  const float* att_v    = (const float*)d_in[16];

  float* outs  = (float*)d_out;
  float* w_out = outs + (size_t)BB * TT * VV;

  char* p = (char*)d_ws;
  auto alloc = [&](size_t bytes) {
    char* q = p; p += (bytes + 255) & ~(size_t)255; return q;
  };
  short* attUt = (short*)alloc((size_t)HH * HH * 2);
  short* attWt = (short*)alloc((size_t)HH * FF * 2);
  short* featb = (short*)alloc((size_t)BB * LL * FF * 2);   // prep only; reused as hall
  short* fcWb  = (short*)alloc((size_t)VV * HH * 2);
  short* Wfb   = (short*)alloc((size_t)4096 * XHLEN * 2);
  short* Wh0b  = (short*)alloc((size_t)HH * FF * 2);
  short* Wc0b  = (short*)alloc((size_t)HH * FF * 2);
  short* mfb   = (short*)alloc((size_t)BB * FF * 2);
  short* xh_h  = (short*)alloc((size_t)BB * XHLEN * 2);
  short* xh_l  = (short*)alloc((size_t)BB * XHLEN * 2);
  float* featp = (float*)alloc((size_t)BB * LL * HH * 4);
  float* cbuf  = (float*)alloc((size_t)BB * HH * 4);
  float* bg    = (float*)alloc(4096 * 4);
  float* pU    = (float*)alloc((size_t)4 * 64 * HH * 4);
  float* pG    = (float*)alloc((size_t)8 * 64 * 4096 * 4);
  int*   bar   = (int*)alloc(2 * sizeof(int));
  // h2 history aliases featb (featb dead after the feat_proj prep GEMM).
  short* hall_h = featb;
  short* hall_l = featb + (size_t)TT * BB * HH;

  // ---- one-time prep ----
  zero2_k<<<1, 1, 0, stream>>>(bar);
  transpose_split_k<<<dim3(32, 32), 256, 0, stream>>>(att_U, attUt, HH, HH);
  transpose_split_k<<<dim3(32, 64), 256, 0, stream>>>(att_W, attWt, FF, HH);
  cast_k<<<2048, 256, 0, stream>>>(features, featb, (size_t)BB * LL * FF);
  cast_k<<<2048, 256, 0, stream>>>(fc_W, fcWb, (size_t)VV * HH);
  cast_k<<<1024, 256, 0, stream>>>(Wh0, Wh0b, (size_t)HH * FF);
  cast_k<<<1024, 256, 0, stream>>>(Wc0, Wc0b, (size_t)HH * FF);
  concat_k<<<dim3(15, 4096), 256, 0, stream>>>(W_ih, W_hh, Wfb);
  setup_k<<<32, 256, 0, stream>>>(b_ih, b_hh, bg, category, xh_h, xh_l);
  mean_k<<<512, 256, 0, stream>>>(features, mfb);

  mgemm_k<false, true, 2><<<dim3(32, 1), 256, 0, stream>>>(
      mfb, nullptr, FF, Wh0b, FF, bh0,
      nullptr, 0, xh_h + XKLEN, xh_l + XKLEN, XHLEN, HH, FF);
  mgemm_k<false, false, 2><<<dim3(32, 1), 256, 0, stream>>>(
      mfb, nullptr, FF, Wc0b, FF, bc0,
      cbuf, HH, nullptr, nullptr, 0, HH, FF);
  mgemm_k<false, false, 4><<<dim3(16, 49), 256, 0, stream>>>(
      featb, nullptr, FF, attWt, FF, nullptr,
      featp, HH, nullptr, nullptr, 0, HH, FF);

  // ---- all 32 timesteps in one persistent kernel ----
  steps_k<<<NBLK, 256, 0, stream>>>(
      attUt, featp, att_v, features, captions, emb, Wfb, bg,
      xh_h, xh_l, cbuf, pU, pG, hall_h, hall_l, w_out, bar, bar + 1);

  // ---- deferred batched fc ----
  bgemm_k<<<dim3(TT, 188), 256, 0, stream>>>(hall_h, hall_l, fcWb, fc_b, outs);
}

// Round 9
// 10479.031 us; speedup vs baseline: 4.6695x; 4.6695x over previous
//
#include <hip/hip_runtime.h>
#include <hip/hip_bf16.h>

#define BB 64
#define TT 32
#define VV 12000
#define EE 512
#define FF 2048
#define CDIM 128
#define HH 1024
#define LL 49
#define XHLEN 3712   /* E + F + C + H */
#define XKLEN 2688   /* E + F + C */

typedef __attribute__((ext_vector_type(8))) short bf16x8;
typedef __attribute__((ext_vector_type(4))) float f32x4;

__device__ __forceinline__ unsigned short bf16_rn(float x) {
  unsigned u = __float_as_uint(x);
  u += 0x7FFFu + ((u >> 16) & 1u);
  return (unsigned short)(u >> 16);
}
__device__ __forceinline__ float bf16_tof(unsigned short h) {
  return __uint_as_float(((unsigned)h) << 16);
}
__device__ __forceinline__ void split2(float x, short& hi, short& lo) {
  unsigned short h = bf16_rn(x);
  float r = x - bf16_tof(h);
  hi = (short)h;
  lo = (short)bf16_rn(r);
}

// ---------------------------------------------------------------------------
// Fused attention: hU = h[b]@att_U (fp32 vector), scores(tanh), softmax,
// context, embedding gather. One block per batch row. Grid 64 x 256.
// ---------------------------------------------------------------------------
__global__ __launch_bounds__(256) void attn_k(
    const float* __restrict__ attU,     // [1024][1024] fp32 (original, k-major)
    const float* __restrict__ featp,    // [B*L][1024] f32
    const float* __restrict__ att_v, const float* __restrict__ features,
    const int* __restrict__ captions, const float* __restrict__ emb,
    short* __restrict__ xh_h, short* __restrict__ xh_l,
    float* __restrict__ w_out, int t)
{
  const int b = blockIdx.x;
  const int tid = threadIdx.x;
  const int wave = tid >> 6, lane = tid & 63;
  __shared__ float h_s[HH];
  __shared__ float hu_s[HH];
  __shared__ float s_w[LL];

  // Phase A: reconstruct h[b] (fp32 = hi + lo) into LDS
#pragma unroll
  for (int j = 0; j < 4; ++j) {
    int i = tid + j * 256;
    h_s[i] = bf16_tof((unsigned short)xh_h[(size_t)b * XHLEN + XKLEN + i])
           + bf16_tof((unsigned short)xh_l[(size_t)b * XHLEN + XKLEN + i]);
  }
  __syncthreads();

  // Phase B: hU[a] = sum_k h[k] * attU[k][a]; thread -> 4 consecutive a
  {
    const int a0 = tid * 4;
    float4 acc = make_float4(0.f, 0.f, 0.f, 0.f);
#pragma unroll 4
    for (int k = 0; k < HH; ++k) {
      float hk = h_s[k];
      float4 u = *(const float4*)&attU[(size_t)k * HH + a0];
      acc.x += hk * u.x; acc.y += hk * u.y;
      acc.z += hk * u.z; acc.w += hk * u.w;
    }
    *(float4*)&hu_s[a0] = acc;
  }
  __syncthreads();

  // Phase C: scores, l striped over waves
  for (int l = wave; l < LL; l += 4) {
    const float* fp = featp + ((size_t)b * LL + l) * HH;
    float acc = 0.f;
    for (int a = lane; a < HH; a += 64)
      acc += tanhf(fp[a] + hu_s[a]) * att_v[a];
#pragma unroll
    for (int off = 32; off > 0; off >>= 1) acc += __shfl_down(acc, off);
    if (lane == 0) s_w[l] = acc;
  }
  __syncthreads();

  // Phase D: softmax over L=49 in wave 0
  if (wave == 0) {
    float v = (lane < LL) ? s_w[lane] : -1e30f;
    float m = v;
#pragma unroll
    for (int off = 32; off > 0; off >>= 1) m = fmaxf(m, __shfl_xor(m, off));
    float e = (lane < LL) ? expf(v - m) : 0.f;
    float s = e;
#pragma unroll
    for (int off = 32; off > 0; off >>= 1) s += __shfl_xor(s, off);
    float ww = e / s;
    if (lane < LL) {
      s_w[lane] = ww;
      w_out[((size_t)b * TT + t) * LL + lane] = ww;
    }
  }
  __syncthreads();

  // Phase E: context -> xh ctx slot (split)
  for (int f = tid; f < FF; f += 256) {
    float acc = 0.f;
#pragma unroll
    for (int l = 0; l < LL; ++l)
      acc += s_w[l] * features[((size_t)b * LL + l) * FF + f];
    short hi, lo; split2(acc, hi, lo);
    xh_h[(size_t)b * XHLEN + EE + f] = hi;
    xh_l[(size_t)b * XHLEN + EE + f] = lo;
  }

  // embedding gather -> xh emb slot
  int cap = captions[b * TT + t];
  for (int j = tid; j < EE; j += 256) {
    short hi, lo; split2(emb[(size_t)cap * EE + j], hi, lo);
    xh_h[(size_t)b * XHLEN + j] = hi;
    xh_l[(size_t)b * XHLEN + j] = lo;
  }
}

// ---------------------------------------------------------------------------
// Fused gates GEMM + LSTM. Block nt owns j-tile nt*16..+15; its 4 MFMA
// col-tiles are the 4 gates {g*1024 + j}. 1024 threads = 16 waves:
// quarter = w&3 (K split 4 x 928), mrow = w>>2 (16-row b-tile).
// After LDS-reduce of quarters 1..3, each quarter-0 lane holds i,f,g,o for
// its (b,j) pairs -> LSTM in-register. Grid 64 x 1024.
// ---------------------------------------------------------------------------
__global__ __launch_bounds__(1024) void glstm_k(
    const short* __restrict__ xh_h_in, const short* __restrict__ xh_l_in,
    const short* __restrict__ Wfb, const float* __restrict__ bg,
    float* __restrict__ cbuf,
    short* __restrict__ xh_h, short* __restrict__ xh_l,
    short* __restrict__ hall_h, short* __restrict__ hall_l, int t)
{
  __shared__ float red[12][64][17];
  const int tid = threadIdx.x;
  const int w = tid >> 6, lane = tid & 63;
  const int quarter = w & 3, mrow = w >> 2;
  const int r = lane & 15, kg = lane >> 4;
  const int nt = blockIdx.x;
  const int ks = quarter * 928;              // XHLEN/4 = 928 = 29*32

  const short* ap  = xh_h_in + (size_t)(mrow * 16 + r) * XHLEN + ks + kg * 8;
  const short* alp = xh_l_in + (size_t)(mrow * 16 + r) * XHLEN + ks + kg * 8;
  const short* wr0 = Wfb + (size_t)(0 * 1024 + nt * 16 + r) * XHLEN + ks + kg * 8;
  const short* wr1 = Wfb + (size_t)(1 * 1024 + nt * 16 + r) * XHLEN + ks + kg * 8;
  const short* wr2 = Wfb + (size_t)(2 * 1024 + nt * 16 + r) * XHLEN + ks + kg * 8;
  const short* wr3 = Wfb + (size_t)(3 * 1024 + nt * 16 + r) * XHLEN + ks + kg * 8;

  f32x4 acc0 = {}, acc1 = {}, acc2 = {}, acc3 = {};
  for (int k0 = 0; k0 < 928; k0 += 32) {
    bf16x8 af  = *(const bf16x8*)(ap + k0);
    bf16x8 alf = *(const bf16x8*)(alp + k0);
    bf16x8 b0 = *(const bf16x8*)(wr0 + k0);
    acc0 = __builtin_amdgcn_mfma_f32_16x16x32_bf16(af,  b0, acc0, 0, 0, 0);
    acc0 = __builtin_amdgcn_mfma_f32_16x16x32_bf16(alf, b0, acc0, 0, 0, 0);
    bf16x8 b1 = *(const bf16x8*)(wr1 + k0);
    acc1 = __builtin_amdgcn_mfma_f32_16x16x32_bf16(af,  b1, acc1, 0, 0, 0);
    acc1 = __builtin_amdgcn_mfma_f32_16x16x32_bf16(alf, b1, acc1, 0, 0, 0);
    bf16x8 b2 = *(const bf16x8*)(wr2 + k0);
    acc2 = __builtin_amdgcn_mfma_f32_16x16x32_bf16(af,  b2, acc2, 0, 0, 0);
    acc2 = __builtin_amdgcn_mfma_f32_16x16x32_bf16(alf, b2, acc2, 0, 0, 0);
    bf16x8 b3 = *(const bf16x8*)(wr3 + k0);
    acc3 = __builtin_amdgcn_mfma_f32_16x16x32_bf16(af,  b3, acc3, 0, 0, 0);
    acc3 = __builtin_amdgcn_mfma_f32_16x16x32_bf16(alf, b3, acc3, 0, 0, 0);
  }

  if (quarter != 0) {
    const int widx = (quarter - 1) * 4 + mrow;
#pragma unroll
    for (int q = 0; q < 4; ++q) {
      red[widx][lane][0 * 4 + q] = acc0[q];
      red[widx][lane][1 * 4 + q] = acc1[q];
      red[widx][lane][2 * 4 + q] = acc2[q];
      red[widx][lane][3 * 4 + q] = acc3[q];
    }
  }
  __syncthreads();
  if (quarter == 0) {
    const int j = nt * 16 + r;
    const float b0 = bg[j], b1 = bg[1024 + j], b2 = bg[2048 + j], b3 = bg[3072 + j];
#pragma unroll
    for (int q = 0; q < 4; ++q) {
      float gi = acc0[q] + b0, gf = acc1[q] + b1;
      float gg = acc2[q] + b2, go = acc3[q] + b3;
#pragma unroll
      for (int p = 0; p < 3; ++p) {
        gi += red[p * 4 + mrow][lane][0 * 4 + q];
        gf += red[p * 4 + mrow][lane][1 * 4 + q];
        gg += red[p * 4 + mrow][lane][2 * 4 + q];
        go += red[p * 4 + mrow][lane][3 * 4 + q];
      }
      const int b = mrow * 16 + kg * 4 + q;
      float si = 1.f / (1.f + expf(-gi));
      float sf = 1.f / (1.f + expf(-gf));
      float so = 1.f / (1.f + expf(-go));
      const size_t ci = (size_t)b * HH + j;
      float cc = sf * cbuf[ci] + si * tanhf(gg);
      float hh = so * tanhf(cc);
      cbuf[ci] = cc;
      short hi, lo; split2(hh, hi, lo);
      xh_h[(size_t)b * XHLEN + XKLEN + j] = hi;
      xh_l[(size_t)b * XHLEN + XKLEN + j] = lo;
      const size_t ho = ((size_t)t * BB + b) * HH + j;
      hall_h[ho] = hi;
      hall_l[ho] = lo;
    }
  }
}

// ---------------------------------------------------------------------------
// Batched fc GEMM: Hall[T*B,H] @ fcW[V,H]^T + fc_b. Grid dim3(TT, 188):
// x-major dispatch => resident blocks cover all t for few n-tiles => W L2-hot.
// ---------------------------------------------------------------------------
__global__ __launch_bounds__(256) void bgemm_k(
    const short* __restrict__ Ah, const short* __restrict__ Al,
    const short* __restrict__ Wb, const float* __restrict__ bias,
    float* __restrict__ outs)
{
  const int tid = threadIdx.x;
  const int w = tid >> 6, l = tid & 63;
  const int r = l & 15, kg = l >> 4;
  const int t = blockIdx.x;
  const int m0 = t * 64;
  const int nrow = blockIdx.y * 64 + w * 16 + r;
  const int nc = nrow < VV ? nrow : VV - 1;
  const short* wp  = Wb + (size_t)nc * HH + kg * 8;
  const short* ap  = Ah + (size_t)(m0 + r) * HH + kg * 8;
  const short* alp = Al + (size_t)(m0 + r) * HH + kg * 8;
  f32x4 acc[4] = {};
  for (int k0 = 0; k0 < HH; k0 += 32) {
    bf16x8 bf = *(const bf16x8*)(wp + k0);
#pragma unroll
    for (int m = 0; m < 4; ++m) {
      bf16x8 af = *(const bf16x8*)(ap + (size_t)(16 * m) * HH + k0);
      acc[m] = __builtin_amdgcn_mfma_f32_16x16x32_bf16(af, bf, acc[m], 0, 0, 0);
      bf16x8 alf = *(const bf16x8*)(alp + (size_t)(16 * m) * HH + k0);
      acc[m] = __builtin_amdgcn_mfma_f32_16x16x32_bf16(alf, bf, acc[m], 0, 0, 0);
    }
  }
  if (nrow < VV) {
    float bv = bias[nrow];
#pragma unroll
    for (int m = 0; m < 4; ++m)
#pragma unroll
      for (int q = 0; q < 4; ++q) {
        int b = m * 16 + kg * 4 + q;
        outs[((size_t)b * TT + t) * VV + nrow] = acc[m][q] + bv;
      }
  }
}

// ---------------------------------------------------------------------------
// MFMA GEMM used in one-time prep (h0, c0, feat_proj).
// ---------------------------------------------------------------------------
template<bool TWOPASS, bool SPLITOUT, int MT>
__global__ __launch_bounds__(256) void mgemm_k(
    const short* __restrict__ Ah, const short* __restrict__ Al, int lda,
    const short* __restrict__ Wb, int ldw,
    const float* __restrict__ bias,
    float* __restrict__ C, int ldc,
    short* __restrict__ Ch, short* __restrict__ Cl, int ldch,
    int N, int K)
{
  const int tid = threadIdx.x;
  const int w = tid >> 6, l = tid & 63;
  const int r = l & 15, kg = l >> 4;
  const int m0 = blockIdx.y * 64;
  const int nslice = (MT == 4) ? w : (w >> 1);
  const int mbase  = (MT == 4) ? 0 : ((w & 1) * 2);
  const int n0 = blockIdx.x * (MT * 16) + nslice * 16;
  const int nrow = n0 + r;
  const int nclmp = nrow < N ? nrow : N - 1;
  const short* wp  = Wb + (size_t)nclmp * ldw + kg * 8;
  const short* ap  = Ah + (size_t)(m0 + mbase * 16 + r) * lda + kg * 8;
  const short* alp = TWOPASS ? (Al + (size_t)(m0 + mbase * 16 + r) * lda + kg * 8)
                             : nullptr;
  f32x4 acc[MT] = {};
  for (int k0 = 0; k0 < K; k0 += 32) {
    bf16x8 bf = *(const bf16x8*)(wp + k0);
#pragma unroll
    for (int m = 0; m < MT; ++m) {
      bf16x8 af = *(const bf16x8*)(ap + (size_t)(16 * m) * lda + k0);
      acc[m] = __builtin_amdgcn_mfma_f32_16x16x32_bf16(af, bf, acc[m], 0, 0, 0);
      if (TWOPASS) {
        bf16x8 alf = *(const bf16x8*)(alp + (size_t)(16 * m) * lda + k0);
        acc[m] = __builtin_amdgcn_mfma_f32_16x16x32_bf16(alf, bf, acc[m], 0, 0, 0);
      }
    }
  }
  if (nrow < N) {
    float bv = bias ? bias[nrow] : 0.f;
#pragma unroll
    for (int m = 0; m < MT; ++m) {
#pragma unroll
      for (int q = 0; q < 4; ++q) {
        int mm = m0 + (mbase + m) * 16 + kg * 4 + q;
        float v = acc[m][q] + bv;
        if (SPLITOUT) {
          short hi, lo; split2(v, hi, lo);
          Ch[(size_t)mm * ldch + nrow] = hi;
          Cl[(size_t)mm * ldch + nrow] = lo;
        } else {
          C[(size_t)mm * ldc + nrow] = v;
        }
      }
    }
  }
}

__global__ __launch_bounds__(256) void transpose_split_k(
    const float* __restrict__ in, short* __restrict__ out, int R, int C)
{
  __shared__ float tile[32][33];
  int bc = blockIdx.x * 32, br = blockIdx.y * 32;
  int tx = threadIdx.x & 31, ty4 = (threadIdx.x >> 5) << 2;
#pragma unroll
  for (int i = 0; i < 4; ++i) {
    int r = br + ty4 + i, c = bc + tx;
    tile[ty4 + i][tx] = (r < R && c < C) ? in[(size_t)r * C + c] : 0.f;
  }
  __syncthreads();
#pragma unroll
  for (int i = 0; i < 4; ++i) {
    int oc = bc + ty4 + i, orr = br + tx;
    if (oc < C && orr < R) out[(size_t)oc * R + orr] = (short)bf16_rn(tile[tx][ty4 + i]);
  }
}

__global__ __launch_bounds__(256) void cast_k(
    const float* __restrict__ in, short* __restrict__ out, size_t n)
{
  for (size_t i = blockIdx.x * 256ULL + threadIdx.x; i < n; i += gridDim.x * 256ULL)
    out[i] = (short)bf16_rn(in[i]);
}

__global__ __launch_bounds__(256) void concat_k(
    const float* __restrict__ wih, const float* __restrict__ whh,
    short* __restrict__ wf)
{
  int k = blockIdx.x * 256 + threadIdx.x;
  int n = blockIdx.y;
  if (k < XHLEN) {
    float v = (k < XKLEN) ? wih[(size_t)n * XKLEN + k]
                          : whh[(size_t)n * HH + (k - XKLEN)];
    wf[(size_t)n * XHLEN + k] = (short)bf16_rn(v);
  }
}

__global__ __launch_bounds__(256) void mean_k(
    const float* __restrict__ feat, short* __restrict__ mf)
{
  int idx = blockIdx.x * 256 + threadIdx.x;
  int b = idx >> 11, f = idx & 2047;
  float s = 0.f;
#pragma unroll
  for (int l = 0; l < LL; ++l) s += feat[((size_t)b * LL + l) * FF + f];
  mf[idx] = (short)bf16_rn(s * (1.f / 49.f));
}

__global__ __launch_bounds__(256) void setup_k(
    const float* __restrict__ b_ih, const float* __restrict__ b_hh,
    float* __restrict__ bg,
    const float* __restrict__ cat,
    short* __restrict__ xh_h, short* __restrict__ xh_l)
{
  int idx = blockIdx.x * 256 + threadIdx.x;
  if (idx < 4096) bg[idx] = b_ih[idx] + b_hh[idx];
  if (idx < BB * CDIM) {
    int b = idx >> 7, j = idx & 127;
    short hi, lo; split2(cat[idx], hi, lo);
    xh_h[(size_t)b * XHLEN + EE + FF + j] = hi;
    xh_l[(size_t)b * XHLEN + EE + FF + j] = lo;
  }
}

extern "C" void kernel_launch(void* const* d_in, const int* in_sizes, int n_in,
                              void* d_out, int out_size, void* d_ws, size_t ws_size,
                              hipStream_t stream) {
  const int*   captions = (const int*)  d_in[0];
  const float* features = (const float*)d_in[1];
  const float* category = (const float*)d_in[2];
  const float* emb      = (const float*)d_in[3];
  const float* W_ih     = (const float*)d_in[4];
  const float* b_ih     = (const float*)d_in[5];
  const float* W_hh     = (const float*)d_in[6];
  const float* b_hh     = (const float*)d_in[7];
  const float* fc_W     = (const float*)d_in[8];
  const float* fc_b     = (const float*)d_in[9];
  const float* Wh0      = (const float*)d_in[10];
  const float* bh0      = (const float*)d_in[11];
  const float* Wc0      = (const float*)d_in[12];
  const float* bc0      = (const float*)d_in[13];
  const float* att_W    = (const float*)d_in[14];
  const float* att_U    = (const float*)d_in[15];
  const float* att_v    = (const float*)d_in[16];

  float* outs  = (float*)d_out;
  float* w_out = outs + (size_t)BB * TT * VV;

  char* p = (char*)d_ws;
  auto alloc = [&](size_t bytes) {
    char* q = p; p += (bytes + 255) & ~(size_t)255; return q;
  };
  short* attWt = (short*)alloc((size_t)HH * FF * 2);
  short* featb = (short*)alloc((size_t)BB * LL * FF * 2);   // prep only; reused as hall
  short* fcWb  = (short*)alloc((size_t)VV * HH * 2);
  short* Wfb   = (short*)alloc((size_t)4096 * XHLEN * 2);
  short* Wh0b  = (short*)alloc((size_t)HH * FF * 2);
  short* Wc0b  = (short*)alloc((size_t)HH * FF * 2);
  short* mfb   = (short*)alloc((size_t)BB * FF * 2);
  short* xh_h  = (short*)alloc((size_t)BB * XHLEN * 2);
  short* xh_l  = (short*)alloc((size_t)BB * XHLEN * 2);
  float* featp = (float*)alloc((size_t)BB * LL * HH * 4);
  float* cbuf  = (float*)alloc((size_t)BB * HH * 4);
  float* bg    = (float*)alloc(4096 * 4);
  // h2 history aliases featb (featb dead after the feat_proj prep GEMM).
  short* hall_h = featb;
  short* hall_l = featb + (size_t)TT * BB * HH;

  // ---- one-time prep ----
  transpose_split_k<<<dim3(32, 64), 256, 0, stream>>>(att_W, attWt, FF, HH);
  cast_k<<<2048, 256, 0, stream>>>(features, featb, (size_t)BB * LL * FF);
  cast_k<<<2048, 256, 0, stream>>>(fc_W, fcWb, (size_t)VV * HH);
  cast_k<<<1024, 256, 0, stream>>>(Wh0, Wh0b, (size_t)HH * FF);
  cast_k<<<1024, 256, 0, stream>>>(Wc0, Wc0b, (size_t)HH * FF);
  concat_k<<<dim3(15, 4096), 256, 0, stream>>>(W_ih, W_hh, Wfb);
  setup_k<<<32, 256, 0, stream>>>(b_ih, b_hh, bg, category, xh_h, xh_l);
  mean_k<<<512, 256, 0, stream>>>(features, mfb);

  mgemm_k<false, true, 2><<<dim3(32, 1), 256, 0, stream>>>(
      mfb, nullptr, FF, Wh0b, FF, bh0,
      nullptr, 0, xh_h + XKLEN, xh_l + XKLEN, XHLEN, HH, FF);
  mgemm_k<false, false, 2><<<dim3(32, 1), 256, 0, stream>>>(
      mfb, nullptr, FF, Wc0b, FF, bc0,
      cbuf, HH, nullptr, nullptr, 0, HH, FF);
  mgemm_k<false, false, 4><<<dim3(16, 49), 256, 0, stream>>>(
      featb, nullptr, FF, attWt, FF, nullptr,
      featp, HH, nullptr, nullptr, 0, HH, FF);

  // ---- timestep loop: 2 dispatches per step ----
  for (int t = 0; t < TT; ++t) {
    attn_k<<<BB, 256, 0, stream>>>(att_U, featp, att_v, features,
                                   captions, emb, xh_h, xh_l, w_out, t);
    glstm_k<<<64, 1024, 0, stream>>>(xh_h, xh_l, Wfb, bg, cbuf,
                                     xh_h, xh_l, hall_h, hall_l, t);
  }

  // ---- deferred batched fc ----
  bgemm_k<<<dim3(TT, 188), 256, 0, stream>>>(hall_h, hall_l, fcWb, fc_b, outs);
}

// Round 10
// 5927.336 us; speedup vs baseline: 8.2553x; 1.7679x over previous
//
#include <hip/hip_runtime.h>
#include <hip/hip_bf16.h>

#define BB 64
#define TT 32
#define VV 12000
#define EE 512
#define FF 2048
#define CDIM 128
#define HH 1024
#define LL 49
#define XHLEN 3712   /* E + F + C + H */
#define XKLEN 2688   /* E + F + C */

typedef __attribute__((ext_vector_type(8))) short bf16x8;
typedef __attribute__((ext_vector_type(4))) float f32x4;

__device__ __forceinline__ unsigned short bf16_rn(float x) {
  unsigned u = __float_as_uint(x);
  u += 0x7FFFu + ((u >> 16) & 1u);
  return (unsigned short)(u >> 16);
}
__device__ __forceinline__ float bf16_tof(unsigned short h) {
  return __uint_as_float(((unsigned)h) << 16);
}
__device__ __forceinline__ void split2(float x, short& hi, short& lo) {
  unsigned short h = bf16_rn(x);
  float r = x - bf16_tof(h);
  hi = (short)h;
  lo = (short)bf16_rn(r);
}

// ---------------------------------------------------------------------------
// Small-M GEMM, K-split across 4 waves + LDS reduce (round-7 proven).
// C[64,N] = (Ah+Al)[64,K] @ Wb[N,K]^T + bias. Grid N/16 x 256.
// ---------------------------------------------------------------------------
template<bool TWOPASS>
__global__ __launch_bounds__(256) void skgemm_k(
    const short* __restrict__ Ah, const short* __restrict__ Al, int lda,
    const short* __restrict__ Wb, int ldw,
    const float* __restrict__ bias,
    float* __restrict__ C, int ldc, int K)
{
  __shared__ float red[4][64][17];
  const int tid = threadIdx.x;
  const int w = tid >> 6, l = tid & 63;
  const int r = l & 15, kg = l >> 4;
  const int n0 = blockIdx.x * 16;
  const int nrow = n0 + r;
  const int kc = K >> 2;
  const int kb = w * kc;
  const short* wp  = Wb + (size_t)nrow * ldw + kb + kg * 8;
  const short* ap  = Ah + (size_t)r * lda + kb + kg * 8;
  const short* alp = TWOPASS ? (Al + (size_t)r * lda + kb + kg * 8) : nullptr;
  f32x4 acc[4] = {};
  for (int k0 = 0; k0 < kc; k0 += 32) {
    bf16x8 bf = *(const bf16x8*)(wp + k0);
#pragma unroll
    for (int m = 0; m < 4; ++m) {
      bf16x8 af = *(const bf16x8*)(ap + (size_t)(16 * m) * lda + k0);
      acc[m] = __builtin_amdgcn_mfma_f32_16x16x32_bf16(af, bf, acc[m], 0, 0, 0);
      if (TWOPASS) {
        bf16x8 alf = *(const bf16x8*)(alp + (size_t)(16 * m) * lda + k0);
        acc[m] = __builtin_amdgcn_mfma_f32_16x16x32_bf16(alf, bf, acc[m], 0, 0, 0);
      }
    }
  }
#pragma unroll
  for (int m = 0; m < 4; ++m)
#pragma unroll
    for (int q = 0; q < 4; ++q)
      red[w][l][m * 4 + q] = acc[m][q];
  __syncthreads();
  const int row = tid >> 2, cg = (tid & 3) * 4;
  const int m = row >> 4, kq = row & 15;
  float4 o;
  float* po = &o.x;
#pragma unroll
  for (int cc = 0; cc < 4; ++cc) {
    int c = cg + cc;
    int sl = (kq >> 2) * 16 + c;
    int ii = m * 4 + (kq & 3);
    float s = red[0][sl][ii] + red[1][sl][ii] + red[2][sl][ii] + red[3][sl][ii];
    po[cc] = s + (bias ? bias[n0 + c] : 0.f);
  }
  *(float4*)&C[(size_t)row * ldc + n0 + cg] = o;
}

// ---------------------------------------------------------------------------
// Attention (round-7 structure, 512 threads): scores(tanh) over hU from
// global, softmax, context, embedding gather. Grid 64 x 512.
// ---------------------------------------------------------------------------
__global__ __launch_bounds__(512) void attn_k(
    const float* __restrict__ featp, const float* __restrict__ hU,
    const float* __restrict__ att_v, const float* __restrict__ features,
    const int* __restrict__ captions, const float* __restrict__ emb,
    short* __restrict__ xh_h, short* __restrict__ xh_l,
    float* __restrict__ w_out, int t)
{
  const int b = blockIdx.x;
  const int tid = threadIdx.x;
  const int wave = tid >> 6, lane = tid & 63;
  __shared__ float s_w[LL];

  for (int l = wave; l < LL; l += 8) {
    const float* fp = featp + ((size_t)b * LL + l) * HH;
    const float* hu = hU + (size_t)b * HH;
    float acc = 0.f;
    for (int a = lane; a < HH; a += 64)
      acc += tanhf(fp[a] + hu[a]) * att_v[a];
#pragma unroll
    for (int off = 32; off > 0; off >>= 1) acc += __shfl_down(acc, off);
    if (lane == 0) s_w[l] = acc;
  }
  __syncthreads();

  if (wave == 0) {
    float v = (lane < LL) ? s_w[lane] : -1e30f;
    float m = v;
#pragma unroll
    for (int off = 32; off > 0; off >>= 1) m = fmaxf(m, __shfl_xor(m, off));
    float e = (lane < LL) ? expf(v - m) : 0.f;
    float s = e;
#pragma unroll
    for (int off = 32; off > 0; off >>= 1) s += __shfl_xor(s, off);
    float ww = e / s;
    if (lane < LL) {
      s_w[lane] = ww;
      w_out[((size_t)b * TT + t) * LL + lane] = ww;
    }
  }
  __syncthreads();

  for (int f = tid; f < FF; f += 512) {
    float acc = 0.f;
#pragma unroll
    for (int l = 0; l < LL; ++l)
      acc += s_w[l] * features[((size_t)b * LL + l) * FF + f];
    short hi, lo; split2(acc, hi, lo);
    xh_h[(size_t)b * XHLEN + EE + f] = hi;
    xh_l[(size_t)b * XHLEN + EE + f] = lo;
  }

  int cap = captions[b * TT + t];
  for (int j = tid; j < EE; j += 512) {
    short hi, lo; split2(emb[(size_t)cap * EE + j], hi, lo);
    xh_h[(size_t)b * XHLEN + j] = hi;
    xh_l[(size_t)b * XHLEN + j] = lo;
  }
}

// ---------------------------------------------------------------------------
// Fused gates GEMM + LSTM (round-9 proven). Grid 64 x 1024.
// ---------------------------------------------------------------------------
__global__ __launch_bounds__(1024) void glstm_k(
    const short* __restrict__ xh_h_in, const short* __restrict__ xh_l_in,
    const short* __restrict__ Wfb, const float* __restrict__ bg,
    float* __restrict__ cbuf,
    short* __restrict__ xh_h, short* __restrict__ xh_l,
    short* __restrict__ hall_h, short* __restrict__ hall_l, int t)
{
  __shared__ float red[12][64][17];
  const int tid = threadIdx.x;
  const int w = tid >> 6, lane = tid & 63;
  const int quarter = w & 3, mrow = w >> 2;
  const int r = lane & 15, kg = lane >> 4;
  const int nt = blockIdx.x;
  const int ks = quarter * 928;

  const short* ap  = xh_h_in + (size_t)(mrow * 16 + r) * XHLEN + ks + kg * 8;
  const short* alp = xh_l_in + (size_t)(mrow * 16 + r) * XHLEN + ks + kg * 8;
  const short* wr0 = Wfb + (size_t)(0 * 1024 + nt * 16 + r) * XHLEN + ks + kg * 8;
  const short* wr1 = Wfb + (size_t)(1 * 1024 + nt * 16 + r) * XHLEN + ks + kg * 8;
  const short* wr2 = Wfb + (size_t)(2 * 1024 + nt * 16 + r) * XHLEN + ks + kg * 8;
  const short* wr3 = Wfb + (size_t)(3 * 1024 + nt * 16 + r) * XHLEN + ks + kg * 8;

  f32x4 acc0 = {}, acc1 = {}, acc2 = {}, acc3 = {};
  for (int k0 = 0; k0 < 928; k0 += 32) {
    bf16x8 af  = *(const bf16x8*)(ap + k0);
    bf16x8 alf = *(const bf16x8*)(alp + k0);
    bf16x8 b0 = *(const bf16x8*)(wr0 + k0);
    acc0 = __builtin_amdgcn_mfma_f32_16x16x32_bf16(af,  b0, acc0, 0, 0, 0);
    acc0 = __builtin_amdgcn_mfma_f32_16x16x32_bf16(alf, b0, acc0, 0, 0, 0);
    bf16x8 b1 = *(const bf16x8*)(wr1 + k0);
    acc1 = __builtin_amdgcn_mfma_f32_16x16x32_bf16(af,  b1, acc1, 0, 0, 0);
    acc1 = __builtin_amdgcn_mfma_f32_16x16x32_bf16(alf, b1, acc1, 0, 0, 0);
    bf16x8 b2 = *(const bf16x8*)(wr2 + k0);
    acc2 = __builtin_amdgcn_mfma_f32_16x16x32_bf16(af,  b2, acc2, 0, 0, 0);
    acc2 = __builtin_amdgcn_mfma_f32_16x16x32_bf16(alf, b2, acc2, 0, 0, 0);
    bf16x8 b3 = *(const bf16x8*)(wr3 + k0);
    acc3 = __builtin_amdgcn_mfma_f32_16x16x32_bf16(af,  b3, acc3, 0, 0, 0);
    acc3 = __builtin_amdgcn_mfma_f32_16x16x32_bf16(alf, b3, acc3, 0, 0, 0);
  }

  if (quarter != 0) {
    const int widx = (quarter - 1) * 4 + mrow;
#pragma unroll
    for (int q = 0; q < 4; ++q) {
      red[widx][lane][0 * 4 + q] = acc0[q];
      red[widx][lane][1 * 4 + q] = acc1[q];
      red[widx][lane][2 * 4 + q] = acc2[q];
      red[widx][lane][3 * 4 + q] = acc3[q];
    }
  }
  __syncthreads();
  if (quarter == 0) {
    const int j = nt * 16 + r;
    const float b0 = bg[j], b1 = bg[1024 + j], b2 = bg[2048 + j], b3 = bg[3072 + j];
#pragma unroll
    for (int q = 0; q < 4; ++q) {
      float gi = acc0[q] + b0, gf = acc1[q] + b1;
      float gg = acc2[q] + b2, go = acc3[q] + b3;
#pragma unroll
      for (int p = 0; p < 3; ++p) {
        gi += red[p * 4 + mrow][lane][0 * 4 + q];
        gf += red[p * 4 + mrow][lane][1 * 4 + q];
        gg += red[p * 4 + mrow][lane][2 * 4 + q];
        go += red[p * 4 + mrow][lane][3 * 4 + q];
      }
      const int b = mrow * 16 + kg * 4 + q;
      float si = 1.f / (1.f + expf(-gi));
      float sf = 1.f / (1.f + expf(-gf));
      float so = 1.f / (1.f + expf(-go));
      const size_t ci = (size_t)b * HH + j;
      float cc = sf * cbuf[ci] + si * tanhf(gg);
      float hh = so * tanhf(cc);
      cbuf[ci] = cc;
      short hi, lo; split2(hh, hi, lo);
      xh_h[(size_t)b * XHLEN + XKLEN + j] = hi;
      xh_l[(size_t)b * XHLEN + XKLEN + j] = lo;
      const size_t ho = ((size_t)t * BB + b) * HH + j;
      hall_h[ho] = hi;
      hall_l[ho] = lo;
    }
  }
}

// ---------------------------------------------------------------------------
// Batched fc GEMM, LDS-staged 128x128 tile, BK=32, padded LDS (row stride 40
// elems -> frag ds_read 2-way bank alias = free). Grid (16 m, 94 n) x-major:
// 16 consecutive blocks share one fc_W panel -> L2-hot. 256 thr, 4 waves;
// wave w owns rows w*32..+31 (2 m-frags) x 128 cols (8 n-frags).
// ---------------------------------------------------------------------------
__global__ __launch_bounds__(256) void bgemm_k(
    const short* __restrict__ Ah, const short* __restrict__ Al,
    const short* __restrict__ Wb, const float* __restrict__ bias,
    float* __restrict__ outs)
{
  __shared__ short lAh[128 * 40];
  __shared__ short lAl[128 * 40];
  __shared__ short lW [128 * 40];
  const int tid = threadIdx.x;
  const int w = tid >> 6, lane = tid & 63;
  const int r = lane & 15, kg = lane >> 4;
  const int m0 = blockIdx.x * 128;
  const int n0 = blockIdx.y * 128;
  const int srow = tid >> 2, scol = (tid & 3) * 8;   // stage coords (64 rows/round)

  f32x4 acc[2][8] = {};
  for (int k0 = 0; k0 < HH; k0 += 32) {
    __syncthreads();
#pragma unroll
    for (int j = 0; j < 2; ++j) {
      const int row = j * 64 + srow;
      bf16x8 va = *(const bf16x8*)&Ah[(size_t)(m0 + row) * HH + k0 + scol];
      bf16x8 vl = *(const bf16x8*)&Al[(size_t)(m0 + row) * HH + k0 + scol];
      int wr = n0 + row; if (wr >= VV) wr = VV - 1;
      bf16x8 vw = *(const bf16x8*)&Wb[(size_t)wr * HH + k0 + scol];
      *(bf16x8*)&lAh[row * 40 + scol] = va;
      *(bf16x8*)&lAl[row * 40 + scol] = vl;
      *(bf16x8*)&lW [row * 40 + scol] = vw;
    }
    __syncthreads();
    bf16x8 ah0 = *(const bf16x8*)&lAh[(w * 32 +  0 + r) * 40 + kg * 8];
    bf16x8 ah1 = *(const bf16x8*)&lAh[(w * 32 + 16 + r) * 40 + kg * 8];
    bf16x8 al0 = *(const bf16x8*)&lAl[(w * 32 +  0 + r) * 40 + kg * 8];
    bf16x8 al1 = *(const bf16x8*)&lAl[(w * 32 + 16 + r) * 40 + kg * 8];
#pragma unroll
    for (int nf = 0; nf < 8; ++nf) {
      bf16x8 wf = *(const bf16x8*)&lW[(nf * 16 + r) * 40 + kg * 8];
      acc[0][nf] = __builtin_amdgcn_mfma_f32_16x16x32_bf16(ah0, wf, acc[0][nf], 0, 0, 0);
      acc[0][nf] = __builtin_amdgcn_mfma_f32_16x16x32_bf16(al0, wf, acc[0][nf], 0, 0, 0);
      acc[1][nf] = __builtin_amdgcn_mfma_f32_16x16x32_bf16(ah1, wf, acc[1][nf], 0, 0, 0);
      acc[1][nf] = __builtin_amdgcn_mfma_f32_16x16x32_bf16(al1, wf, acc[1][nf], 0, 0, 0);
    }
  }
#pragma unroll
  for (int nf = 0; nf < 8; ++nf) {
    const int colv = n0 + nf * 16 + r;
    if (colv < VV) {
      const float bv = bias[colv];
#pragma unroll
      for (int mf = 0; mf < 2; ++mf)
#pragma unroll
        for (int q = 0; q < 4; ++q) {
          const int grow = m0 + w * 32 + mf * 16 + kg * 4 + q;  // = t*64 + b
          const int t = grow >> 6, b = grow & 63;
          outs[((size_t)b * TT + t) * VV + colv] = acc[mf][nf][q] + bv;
        }
    }
  }
}

// ---------------------------------------------------------------------------
// MFMA GEMM used in one-time prep (h0, c0, feat_proj).
// ---------------------------------------------------------------------------
template<bool TWOPASS, bool SPLITOUT, int MT>
__global__ __launch_bounds__(256) void mgemm_k(
    const short* __restrict__ Ah, const short* __restrict__ Al, int lda,
    const short* __restrict__ Wb, int ldw,
    const float* __restrict__ bias,
    float* __restrict__ C, int ldc,
    short* __restrict__ Ch, short* __restrict__ Cl, int ldch,
    int N, int K)
{
  const int tid = threadIdx.x;
  const int w = tid >> 6, l = tid & 63;
  const int r = l & 15, kg = l >> 4;
  const int m0 = blockIdx.y * 64;
  const int nslice = (MT == 4) ? w : (w >> 1);
  const int mbase  = (MT == 4) ? 0 : ((w & 1) * 2);
  const int n0 = blockIdx.x * (MT * 16) + nslice * 16;
  const int nrow = n0 + r;
  const int nclmp = nrow < N ? nrow : N - 1;
  const short* wp  = Wb + (size_t)nclmp * ldw + kg * 8;
  const short* ap  = Ah + (size_t)(m0 + mbase * 16 + r) * lda + kg * 8;
  const short* alp = TWOPASS ? (Al + (size_t)(m0 + mbase * 16 + r) * lda + kg * 8)
                             : nullptr;
  f32x4 acc[MT] = {};
  for (int k0 = 0; k0 < K; k0 += 32) {
    bf16x8 bf = *(const bf16x8*)(wp + k0);
#pragma unroll
    for (int m = 0; m < MT; ++m) {
      bf16x8 af = *(const bf16x8*)(ap + (size_t)(16 * m) * lda + k0);
      acc[m] = __builtin_amdgcn_mfma_f32_16x16x32_bf16(af, bf, acc[m], 0, 0, 0);
      if (TWOPASS) {
        bf16x8 alf = *(const bf16x8*)(alp + (size_t)(16 * m) * lda + k0);
        acc[m] = __builtin_amdgcn_mfma_f32_16x16x32_bf16(alf, bf, acc[m], 0, 0, 0);
      }
    }
  }
  if (nrow < N) {
    float bv = bias ? bias[nrow] : 0.f;
#pragma unroll
    for (int m = 0; m < MT; ++m) {
#pragma unroll
      for (int q = 0; q < 4; ++q) {
        int mm = m0 + (mbase + m) * 16 + kg * 4 + q;
        float v = acc[m][q] + bv;
        if (SPLITOUT) {
          short hi, lo; split2(v, hi, lo);
          Ch[(size_t)mm * ldch + nrow] = hi;
          Cl[(size_t)mm * ldch + nrow] = lo;
        } else {
          C[(size_t)mm * ldc + nrow] = v;
        }
      }
    }
  }
}

__global__ __launch_bounds__(256) void transpose_split_k(
    const float* __restrict__ in, short* __restrict__ out, int R, int C)
{
  __shared__ float tile[32][33];
  int bc = blockIdx.x * 32, br = blockIdx.y * 32;
  int tx = threadIdx.x & 31, ty4 = (threadIdx.x >> 5) << 2;
#pragma unroll
  for (int i = 0; i < 4; ++i) {
    int r = br + ty4 + i, c = bc + tx;
    tile[ty4 + i][tx] = (r < R && c < C) ? in[(size_t)r * C + c] : 0.f;
  }
  __syncthreads();
#pragma unroll
  for (int i = 0; i < 4; ++i) {
    int oc = bc + ty4 + i, orr = br + tx;
    if (oc < C && orr < R) out[(size_t)oc * R + orr] = (short)bf16_rn(tile[tx][ty4 + i]);
  }
}

__global__ __launch_bounds__(256) void cast_k(
    const float* __restrict__ in, short* __restrict__ out, size_t n)
{
  for (size_t i = blockIdx.x * 256ULL + threadIdx.x; i < n; i += gridDim.x * 256ULL)
    out[i] = (short)bf16_rn(in[i]);
}

__global__ __launch_bounds__(256) void concat_k(
    const float* __restrict__ wih, const float* __restrict__ whh,
    short* __restrict__ wf)
{
  int k = blockIdx.x * 256 + threadIdx.x;
  int n = blockIdx.y;
  if (k < XHLEN) {
    float v = (k < XKLEN) ? wih[(size_t)n * XKLEN + k]
                          : whh[(size_t)n * HH + (k - XKLEN)];
    wf[(size_t)n * XHLEN + k] = (short)bf16_rn(v);
  }
}

__global__ __launch_bounds__(256) void mean_k(
    const float* __restrict__ feat, short* __restrict__ mf)
{
  int idx = blockIdx.x * 256 + threadIdx.x;
  int b = idx >> 11, f = idx & 2047;
  float s = 0.f;
#pragma unroll
  for (int l = 0; l < LL; ++l) s += feat[((size_t)b * LL + l) * FF + f];
  mf[idx] = (short)bf16_rn(s * (1.f / 49.f));
}

__global__ __launch_bounds__(256) void setup_k(
    const float* __restrict__ b_ih, const float* __restrict__ b_hh,
    float* __restrict__ bg,
    const float* __restrict__ cat,
    short* __restrict__ xh_h, short* __restrict__ xh_l)
{
  int idx = blockIdx.x * 256 + threadIdx.x;
  if (idx < 4096) bg[idx] = b_ih[idx] + b_hh[idx];
  if (idx < BB * CDIM) {
    int b = idx >> 7, j = idx & 127;
    short hi, lo; split2(cat[idx], hi, lo);
    xh_h[(size_t)b * XHLEN + EE + FF + j] = hi;
    xh_l[(size_t)b * XHLEN + EE + FF + j] = lo;
  }
}

extern "C" void kernel_launch(void* const* d_in, const int* in_sizes, int n_in,
                              void* d_out, int out_size, void* d_ws, size_t ws_size,
                              hipStream_t stream) {
  const int*   captions = (const int*)  d_in[0];
  const float* features = (const float*)d_in[1];
  const float* category = (const float*)d_in[2];
  const float* emb      = (const float*)d_in[3];
  const float* W_ih     = (const float*)d_in[4];
  const float* b_ih     = (const float*)d_in[5];
  const float* W_hh     = (const float*)d_in[6];
  const float* b_hh     = (const float*)d_in[7];
  const float* fc_W     = (const float*)d_in[8];
  const float* fc_b     = (const float*)d_in[9];
  const float* Wh0      = (const float*)d_in[10];
  const float* bh0      = (const float*)d_in[11];
  const float* Wc0      = (const float*)d_in[12];
  const float* bc0      = (const float*)d_in[13];
  const float* att_W    = (const float*)d_in[14];
  const float* att_U    = (const float*)d_in[15];
  const float* att_v    = (const float*)d_in[16];

  float* outs  = (float*)d_out;
  float* w_out = outs + (size_t)BB * TT * VV;

  char* p = (char*)d_ws;
  auto alloc = [&](size_t bytes) {
    char* q = p; p += (bytes + 255) & ~(size_t)255; return q;
  };
  short* attUt = (short*)alloc((size_t)HH * HH * 2);
  short* attWt = (short*)alloc((size_t)HH * FF * 2);
  short* featb = (short*)alloc((size_t)BB * LL * FF * 2);   // prep only; reused as hall
  short* fcWb  = (short*)alloc((size_t)VV * HH * 2);
  short* Wfb   = (short*)alloc((size_t)4096 * XHLEN * 2);
  short* Wh0b  = (short*)alloc((size_t)HH * FF * 2);
  short* Wc0b  = (short*)alloc((size_t)HH * FF * 2);
  short* mfb   = (short*)alloc((size_t)BB * FF * 2);
  short* xh_h  = (short*)alloc((size_t)BB * XHLEN * 2);
  short* xh_l  = (short*)alloc((size_t)BB * XHLEN * 2);
  float* featp = (float*)alloc((size_t)BB * LL * HH * 4);
  float* cbuf  = (float*)alloc((size_t)BB * HH * 4);
  float* hU    = (float*)alloc((size_t)BB * HH * 4);
  float* bg    = (float*)alloc(4096 * 4);
  // h2 history aliases featb (featb dead after the feat_proj prep GEMM).
  short* hall_h = featb;
  short* hall_l = featb + (size_t)TT * BB * HH;

  // ---- one-time prep ----
  transpose_split_k<<<dim3(32, 32), 256, 0, stream>>>(att_U, attUt, HH, HH);
  transpose_split_k<<<dim3(32, 64), 256, 0, stream>>>(att_W, attWt, FF, HH);
  cast_k<<<2048, 256, 0, stream>>>(features, featb, (size_t)BB * LL * FF);
  cast_k<<<2048, 256, 0, stream>>>(fc_W, fcWb, (size_t)VV * HH);
  cast_k<<<1024, 256, 0, stream>>>(Wh0, Wh0b, (size_t)HH * FF);
  cast_k<<<1024, 256, 0, stream>>>(Wc0, Wc0b, (size_t)HH * FF);
  concat_k<<<dim3(15, 4096), 256, 0, stream>>>(W_ih, W_hh, Wfb);
  setup_k<<<32, 256, 0, stream>>>(b_ih, b_hh, bg, category, xh_h, xh_l);
  mean_k<<<512, 256, 0, stream>>>(features, mfb);

  mgemm_k<false, true, 2><<<dim3(32, 1), 256, 0, stream>>>(
      mfb, nullptr, FF, Wh0b, FF, bh0,
      nullptr, 0, xh_h + XKLEN, xh_l + XKLEN, XHLEN, HH, FF);
  mgemm_k<false, false, 2><<<dim3(32, 1), 256, 0, stream>>>(
      mfb, nullptr, FF, Wc0b, FF, bc0,
      cbuf, HH, nullptr, nullptr, 0, HH, FF);
  mgemm_k<false, false, 4><<<dim3(16, 49), 256, 0, stream>>>(
      featb, nullptr, FF, attWt, FF, nullptr,
      featp, HH, nullptr, nullptr, 0, HH, FF);

  // ---- timestep loop: 3 dispatches per step ----
  for (int t = 0; t < TT; ++t) {
    skgemm_k<true><<<64, 256, 0, stream>>>(
        xh_h + XKLEN, xh_l + XKLEN, XHLEN, attUt, HH, nullptr, hU, HH, HH);
    attn_k<<<BB, 512, 0, stream>>>(featp, hU, att_v, features,
                                   captions, emb, xh_h, xh_l, w_out, t);
    glstm_k<<<64, 1024, 0, stream>>>(xh_h, xh_l, Wfb, bg, cbuf,
                                     xh_h, xh_l, hall_h, hall_l, t);
  }

  // ---- deferred batched fc: LDS-staged 128x128 tiles ----
  bgemm_k<<<dim3(16, 94), 256, 0, stream>>>(hall_h, hall_l, fcWb, fc_b, outs);
}

// Round 12
// 3356.161 us; speedup vs baseline: 14.5798x; 1.7661x over previous
//
#include <hip/hip_runtime.h>
#include <hip/hip_bf16.h>

#define BB 64
#define TT 32
#define VV 12000
#define EE 512
#define FF 2048
#define CDIM 128
#define HH 1024
#define LL 49
#define XHLEN 3712   /* E + F + C + H */
#define XKLEN 2688   /* E + F + C */

typedef __attribute__((ext_vector_type(8))) short bf16x8;
typedef __attribute__((ext_vector_type(4))) float f32x4;

__device__ __forceinline__ unsigned short bf16_rn(float x) {
  unsigned u = __float_as_uint(x);
  u += 0x7FFFu + ((u >> 16) & 1u);
  return (unsigned short)(u >> 16);
}
__device__ __forceinline__ float bf16_tof(unsigned short h) {
  return __uint_as_float(((unsigned)h) << 16);
}
__device__ __forceinline__ void split2(float x, short& hi, short& lo) {
  unsigned short h = bf16_rn(x);
  float r = x - bf16_tof(h);
  hi = (short)h;
  lo = (short)bf16_rn(r);
}

// ---------------------------------------------------------------------------
// D1: hU tile + partial scores. Grid (64 a-tiles, 2 b-halves) x 256.
// Block (nt, mh): 4 waves K-split 4x256 compute hU[32 b][16 a] (hi/lo 2-pass,
// LDS-reduced), then partS[b][nt][l] = sum_{a in tile} tanh(featp+hU)*v[a].
// ---------------------------------------------------------------------------
__global__ __launch_bounds__(256) void hupart_k(
    const short* __restrict__ xh_h, const short* __restrict__ xh_l,
    const short* __restrict__ attUt,   // [1024][1024] bf16 = att_U^T
    const float* __restrict__ featp,   // [B*L][1024] f32
    const float* __restrict__ att_v,
    float* __restrict__ partS)         // [B][64][49]
{
  __shared__ float red[4][64][9];
  __shared__ float hu_s[32][17];
  __shared__ float av_s[16];
  const int tid = threadIdx.x;
  const int w = tid >> 6, lane = tid & 63;
  const int r = lane & 15, kg = lane >> 4;
  const int nt = blockIdx.x, mh = blockIdx.y;
  const int kb = w * 256;

  if (tid < 16) av_s[tid] = att_v[nt * 16 + tid];

  const short* wp  = attUt + (size_t)(nt * 16 + r) * HH + kb + kg * 8;
  const short* ap  = xh_h + (size_t)(mh * 32 + r) * XHLEN + XKLEN + kb + kg * 8;
  const short* alp = xh_l + (size_t)(mh * 32 + r) * XHLEN + XKLEN + kb + kg * 8;
  f32x4 acc[2] = {};
#pragma unroll
  for (int k0 = 0; k0 < 256; k0 += 32) {
    bf16x8 bf = *(const bf16x8*)(wp + k0);
#pragma unroll
    for (int m = 0; m < 2; ++m) {
      bf16x8 af = *(const bf16x8*)(ap + (size_t)(16 * m) * XHLEN + k0);
      acc[m] = __builtin_amdgcn_mfma_f32_16x16x32_bf16(af, bf, acc[m], 0, 0, 0);
      bf16x8 alf = *(const bf16x8*)(alp + (size_t)(16 * m) * XHLEN + k0);
      acc[m] = __builtin_amdgcn_mfma_f32_16x16x32_bf16(alf, bf, acc[m], 0, 0, 0);
    }
  }
#pragma unroll
  for (int m = 0; m < 2; ++m)
#pragma unroll
    for (int q = 0; q < 4; ++q)
      red[w][lane][m * 4 + q] = acc[m][q];
  __syncthreads();

  // assemble hU[32][16] from the 4 K-quarters
  for (int idx = tid; idx < 512; idx += 256) {
    const int bl = idx >> 4, a = idx & 15;
    const int m = bl >> 4, wi = bl & 15;
    const int sl = (wi >> 2) * 16 + a;
    const int ii = m * 4 + (wi & 3);
    hu_s[bl][a] = red[0][sl][ii] + red[1][sl][ii] + red[2][sl][ii] + red[3][sl][ii];
  }
  __syncthreads();

  // partial scores for this a-slice
  for (int task = tid; task < 32 * LL; task += 256) {
    const int bl = task / LL, l = task - bl * LL;
    const int b = mh * 32 + bl;
    const float* fp = featp + ((size_t)b * LL + l) * HH + nt * 16;
    float s = 0.f;
#pragma unroll
    for (int a = 0; a < 16; ++a)
      s += tanhf(fp[a] + hu_s[bl][a]) * av_s[a];
    partS[((size_t)b * 64 + nt) * LL + l] = s;
  }
}

// ---------------------------------------------------------------------------
// D2: softmax + context + embedding. Grid (64 b, 2 f-halves) x 256.
// Both halves recompute the (trivial) softmax; fh==0 writes w_out.
// ---------------------------------------------------------------------------
__global__ __launch_bounds__(256) void attn2_k(
    const float* __restrict__ partS, const float* __restrict__ features,
    const int* __restrict__ captions, const float* __restrict__ emb,
    short* __restrict__ xh_h, short* __restrict__ xh_l,
    float* __restrict__ w_out, int t)
{
  const int b = blockIdx.x, fh = blockIdx.y;
  const int tid = threadIdx.x;
  const int wave = tid >> 6, lane = tid & 63;
  __shared__ float s_w[LL];

  if (tid < LL) {
    float s = 0.f;
    const float* ps = partS + (size_t)b * 64 * LL + tid;
#pragma unroll 8
    for (int nt = 0; nt < 64; ++nt) s += ps[nt * LL];
    s_w[tid] = s;
  }
  __syncthreads();

  if (wave == 0) {
    float v = (lane < LL) ? s_w[lane] : -1e30f;
    float m = v;
#pragma unroll
    for (int off = 32; off > 0; off >>= 1) m = fmaxf(m, __shfl_xor(m, off));
    float e = (lane < LL) ? expf(v - m) : 0.f;
    float s = e;
#pragma unroll
    for (int off = 32; off > 0; off >>= 1) s += __shfl_xor(s, off);
    float ww = e / s;
    if (lane < LL) {
      s_w[lane] = ww;
      if (fh == 0) w_out[((size_t)b * TT + t) * LL + lane] = ww;
    }
  }
  __syncthreads();

  // context over this f-half
  for (int f = fh * 1024 + tid; f < fh * 1024 + 1024; f += 256) {
    float acc = 0.f;
#pragma unroll
    for (int l = 0; l < LL; ++l)
      acc += s_w[l] * features[((size_t)b * LL + l) * FF + f];
    short hi, lo; split2(acc, hi, lo);
    xh_h[(size_t)b * XHLEN + EE + f] = hi;
    xh_l[(size_t)b * XHLEN + EE + f] = lo;
  }

  // embedding gather, this half
  const int cap = captions[b * TT + t];
  {
    const int j = fh * 256 + tid;
    short hi, lo; split2(emb[(size_t)cap * EE + j], hi, lo);
    xh_h[(size_t)b * XHLEN + j] = hi;
    xh_l[(size_t)b * XHLEN + j] = lo;
  }
}

// ---------------------------------------------------------------------------
// D3: fused gates GEMM + LSTM, batch-split. Grid (64 j-tiles, 4 b-quarters)
// x 256. Block (nt, mq): 4 waves K-split 4x928; wave accumulates the 4 gate
// col-tiles for b-rows mq*16..+15. LDS-reduce, LSTM in epilogue.
// ---------------------------------------------------------------------------
__global__ __launch_bounds__(256) void glstm2_k(
    const short* __restrict__ xh_h_in, const short* __restrict__ xh_l_in,
    const short* __restrict__ Wfb, const float* __restrict__ bg,
    float* __restrict__ cbuf,
    short* __restrict__ xh_h, short* __restrict__ xh_l,
    short* __restrict__ hall_h, short* __restrict__ hall_l, int t)
{
  __shared__ float red[3][64][17];
  const int tid = threadIdx.x;
  const int w = tid >> 6, lane = tid & 63;
  const int r = lane & 15, kg = lane >> 4;
  const int nt = blockIdx.x, mq = blockIdx.y;
  const int ks = w * 928;                       // K quarter

  const short* ap  = xh_h_in + (size_t)(mq * 16 + r) * XHLEN + ks + kg * 8;
  const short* alp = xh_l_in + (size_t)(mq * 16 + r) * XHLEN + ks + kg * 8;
  const short* wr0 = Wfb + (size_t)(0 * 1024 + nt * 16 + r) * XHLEN + ks + kg * 8;
  const short* wr1 = Wfb + (size_t)(1 * 1024 + nt * 16 + r) * XHLEN + ks + kg * 8;
  const short* wr2 = Wfb + (size_t)(2 * 1024 + nt * 16 + r) * XHLEN + ks + kg * 8;
  const short* wr3 = Wfb + (size_t)(3 * 1024 + nt * 16 + r) * XHLEN + ks + kg * 8;

  f32x4 acc0 = {}, acc1 = {}, acc2 = {}, acc3 = {};
  for (int k0 = 0; k0 < 928; k0 += 32) {
    bf16x8 af  = *(const bf16x8*)(ap + k0);
    bf16x8 alf = *(const bf16x8*)(alp + k0);
    bf16x8 b0 = *(const bf16x8*)(wr0 + k0);
    acc0 = __builtin_amdgcn_mfma_f32_16x16x32_bf16(af,  b0, acc0, 0, 0, 0);
    acc0 = __builtin_amdgcn_mfma_f32_16x16x32_bf16(alf, b0, acc0, 0, 0, 0);
    bf16x8 b1 = *(const bf16x8*)(wr1 + k0);
    acc1 = __builtin_amdgcn_mfma_f32_16x16x32_bf16(af,  b1, acc1, 0, 0, 0);
    acc1 = __builtin_amdgcn_mfma_f32_16x16x32_bf16(alf, b1, acc1, 0, 0, 0);
    bf16x8 b2 = *(const bf16x8*)(wr2 + k0);
    acc2 = __builtin_amdgcn_mfma_f32_16x16x32_bf16(af,  b2, acc2, 0, 0, 0);
    acc2 = __builtin_amdgcn_mfma_f32_16x16x32_bf16(alf, b2, acc2, 0, 0, 0);
    bf16x8 b3 = *(const bf16x8*)(wr3 + k0);
    acc3 = __builtin_amdgcn_mfma_f32_16x16x32_bf16(af,  b3, acc3, 0, 0, 0);
    acc3 = __builtin_amdgcn_mfma_f32_16x16x32_bf16(alf, b3, acc3, 0, 0, 0);
  }

  if (w != 0) {
#pragma unroll
    for (int q = 0; q < 4; ++q) {
      red[w - 1][lane][0 * 4 + q] = acc0[q];
      red[w - 1][lane][1 * 4 + q] = acc1[q];
      red[w - 1][lane][2 * 4 + q] = acc2[q];
      red[w - 1][lane][3 * 4 + q] = acc3[q];
    }
  }
  __syncthreads();
  if (w == 0) {
    const int j = nt * 16 + r;
    const float b0 = bg[j], b1 = bg[1024 + j], b2 = bg[2048 + j], b3 = bg[3072 + j];
#pragma unroll
    for (int q = 0; q < 4; ++q) {
      float gi = acc0[q] + b0, gf = acc1[q] + b1;
      float gg = acc2[q] + b2, go = acc3[q] + b3;
#pragma unroll
      for (int p = 0; p < 3; ++p) {
        gi += red[p][lane][0 * 4 + q];
        gf += red[p][lane][1 * 4 + q];
        gg += red[p][lane][2 * 4 + q];
        go += red[p][lane][3 * 4 + q];
      }
      const int b = mq * 16 + kg * 4 + q;
      float si = 1.f / (1.f + expf(-gi));
      float sf = 1.f / (1.f + expf(-gf));
      float so = 1.f / (1.f + expf(-go));
      const size_t ci = (size_t)b * HH + j;
      float cc = sf * cbuf[ci] + si * tanhf(gg);
      float hh = so * tanhf(cc);
      cbuf[ci] = cc;
      short hi, lo; split2(hh, hi, lo);
      xh_h[(size_t)b * XHLEN + XKLEN + j] = hi;
      xh_l[(size_t)b * XHLEN + XKLEN + j] = lo;
      const size_t ho = ((size_t)t * BB + b) * HH + j;
      hall_h[ho] = hi;
      hall_l[ho] = lo;
    }
  }
}

// ---------------------------------------------------------------------------
// Batched fc GEMM, LDS-staged 128x128 tile (round-10 proven). Grid (16, 94).
// ---------------------------------------------------------------------------
__global__ __launch_bounds__(256) void bgemm_k(
    const short* __restrict__ Ah, const short* __restrict__ Al,
    const short* __restrict__ Wb, const float* __restrict__ bias,
    float* __restrict__ outs)
{
  __shared__ short lAh[128 * 40];
  __shared__ short lAl[128 * 40];
  __shared__ short lW [128 * 40];
  const int tid = threadIdx.x;
  const int w = tid >> 6, lane = tid & 63;
  const int r = lane & 15, kg = lane >> 4;
  const int m0 = blockIdx.x * 128;
  const int n0 = blockIdx.y * 128;
  const int srow = tid >> 2, scol = (tid & 3) * 8;

  f32x4 acc[2][8] = {};
  for (int k0 = 0; k0 < HH; k0 += 32) {
    __syncthreads();
#pragma unroll
    for (int j = 0; j < 2; ++j) {
      const int row = j * 64 + srow;
      bf16x8 va = *(const bf16x8*)&Ah[(size_t)(m0 + row) * HH + k0 + scol];
      bf16x8 vl = *(const bf16x8*)&Al[(size_t)(m0 + row) * HH + k0 + scol];
      int wr = n0 + row; if (wr >= VV) wr = VV - 1;
      bf16x8 vw = *(const bf16x8*)&Wb[(size_t)wr * HH + k0 + scol];
      *(bf16x8*)&lAh[row * 40 + scol] = va;
      *(bf16x8*)&lAl[row * 40 + scol] = vl;
      *(bf16x8*)&lW [row * 40 + scol] = vw;
    }
    __syncthreads();
    bf16x8 ah0 = *(const bf16x8*)&lAh[(w * 32 +  0 + r) * 40 + kg * 8];
    bf16x8 ah1 = *(const bf16x8*)&lAh[(w * 32 + 16 + r) * 40 + kg * 8];
    bf16x8 al0 = *(const bf16x8*)&lAl[(w * 32 +  0 + r) * 40 + kg * 8];
    bf16x8 al1 = *(const bf16x8*)&lAl[(w * 32 + 16 + r) * 40 + kg * 8];
#pragma unroll
    for (int nf = 0; nf < 8; ++nf) {
      bf16x8 wf = *(const bf16x8*)&lW[(nf * 16 + r) * 40 + kg * 8];
      acc[0][nf] = __builtin_amdgcn_mfma_f32_16x16x32_bf16(ah0, wf, acc[0][nf], 0, 0, 0);
      acc[0][nf] = __builtin_amdgcn_mfma_f32_16x16x32_bf16(al0, wf, acc[0][nf], 0, 0, 0);
      acc[1][nf] = __builtin_amdgcn_mfma_f32_16x16x32_bf16(ah1, wf, acc[1][nf], 0, 0, 0);
      acc[1][nf] = __builtin_amdgcn_mfma_f32_16x16x32_bf16(al1, wf, acc[1][nf], 0, 0, 0);
    }
  }
#pragma unroll
  for (int nf = 0; nf < 8; ++nf) {
    const int colv = n0 + nf * 16 + r;
    if (colv < VV) {
      const float bv = bias[colv];
#pragma unroll
      for (int mf = 0; mf < 2; ++mf)
#pragma unroll
        for (int q = 0; q < 4; ++q) {
          const int grow = m0 + w * 32 + mf * 16 + kg * 4 + q;  // = t*64 + b
          const int t = grow >> 6, b = grow & 63;
          outs[((size_t)b * TT + t) * VV + colv] = acc[mf][nf][q] + bv;
        }
    }
  }
}

// ---------------------------------------------------------------------------
// MFMA GEMM used in one-time prep (h0, c0, feat_proj).
// ---------------------------------------------------------------------------
template<bool TWOPASS, bool SPLITOUT, int MT>
__global__ __launch_bounds__(256) void mgemm_k(
    const short* __restrict__ Ah, const short* __restrict__ Al, int lda,
    const short* __restrict__ Wb, int ldw,
    const float* __restrict__ bias,
    float* __restrict__ C, int ldc,
    short* __restrict__ Ch, short* __restrict__ Cl, int ldch,
    int N, int K)
{
  const int tid = threadIdx.x;
  const int w = tid >> 6, l = tid & 63;
  const int r = l & 15, kg = l >> 4;
  const int m0 = blockIdx.y * 64;
  const int nslice = (MT == 4) ? w : (w >> 1);
  const int mbase  = (MT == 4) ? 0 : ((w & 1) * 2);
  const int n0 = blockIdx.x * (MT * 16) + nslice * 16;
  const int nrow = n0 + r;
  const int nclmp = nrow < N ? nrow : N - 1;
  const short* wp  = Wb + (size_t)nclmp * ldw + kg * 8;
  const short* ap  = Ah + (size_t)(m0 + mbase * 16 + r) * lda + kg * 8;
  const short* alp = TWOPASS ? (Al + (size_t)(m0 + mbase * 16 + r) * lda + kg * 8)
                             : nullptr;
  f32x4 acc[MT] = {};
  for (int k0 = 0; k0 < K; k0 += 32) {
    bf16x8 bf = *(const bf16x8*)(wp + k0);
#pragma unroll
    for (int m = 0; m < MT; ++m) {
      bf16x8 af = *(const bf16x8*)(ap + (size_t)(16 * m) * lda + k0);
      acc[m] = __builtin_amdgcn_mfma_f32_16x16x32_bf16(af, bf, acc[m], 0, 0, 0);
      if (TWOPASS) {
        bf16x8 alf = *(const bf16x8*)(alp + (size_t)(16 * m) * lda + k0);
        acc[m] = __builtin_amdgcn_mfma_f32_16x16x32_bf16(alf, bf, acc[m], 0, 0, 0);
      }
    }
  }
  if (nrow < N) {
    float bv = bias ? bias[nrow] : 0.f;
#pragma unroll
    for (int m = 0; m < MT; ++m) {
#pragma unroll
      for (int q = 0; q < 4; ++q) {
        int mm = m0 + (mbase + m) * 16 + kg * 4 + q;
        float v = acc[m][q] + bv;
        if (SPLITOUT) {
          short hi, lo; split2(v, hi, lo);
          Ch[(size_t)mm * ldch + nrow] = hi;
          Cl[(size_t)mm * ldch + nrow] = lo;
        } else {
          C[(size_t)mm * ldc + nrow] = v;
        }
      }
    }
  }
}

__global__ __launch_bounds__(256) void transpose_split_k(
    const float* __restrict__ in, short* __restrict__ out, int R, int C)
{
  __shared__ float tile[32][33];
  int bc = blockIdx.x * 32, br = blockIdx.y * 32;
  int tx = threadIdx.x & 31, ty4 = (threadIdx.x >> 5) << 2;
#pragma unroll
  for (int i = 0; i < 4; ++i) {
    int r = br + ty4 + i, c = bc + tx;
    tile[ty4 + i][tx] = (r < R && c < C) ? in[(size_t)r * C + c] : 0.f;
  }
  __syncthreads();
#pragma unroll
  for (int i = 0; i < 4; ++i) {
    int oc = bc + ty4 + i, orr = br + tx;
    if (oc < C && orr < R) out[(size_t)oc * R + orr] = (short)bf16_rn(tile[tx][ty4 + i]);
  }
}

__global__ __launch_bounds__(256) void cast_k(
    const float* __restrict__ in, short* __restrict__ out, size_t n)
{
  for (size_t i = blockIdx.x * 256ULL + threadIdx.x; i < n; i += gridDim.x * 256ULL)
    out[i] = (short)bf16_rn(in[i]);
}

__global__ __launch_bounds__(256) void concat_k(
    const float* __restrict__ wih, const float* __restrict__ whh,
    short* __restrict__ wf)
{
  int k = blockIdx.x * 256 + threadIdx.x;
  int n = blockIdx.y;
  if (k < XHLEN) {
    float v = (k < XKLEN) ? wih[(size_t)n * XKLEN + k]
                          : whh[(size_t)n * HH + (k - XKLEN)];
    wf[(size_t)n * XHLEN + k] = (short)bf16_rn(v);
  }
}

__global__ __launch_bounds__(256) void mean_k(
    const float* __restrict__ feat, short* __restrict__ mf)
{
  int idx = blockIdx.x * 256 + threadIdx.x;
  int b = idx >> 11, f = idx & 2047;
  float s = 0.f;
#pragma unroll
  for (int l = 0; l < LL; ++l) s += feat[((size_t)b * LL + l) * FF + f];
  mf[idx] = (short)bf16_rn(s * (1.f / 49.f));
}

__global__ __launch_bounds__(256) void setup_k(
    const float* __restrict__ b_ih, const float* __restrict__ b_hh,
    float* __restrict__ bg,
    const float* __restrict__ cat,
    short* __restrict__ xh_h, short* __restrict__ xh_l)
{
  int idx = blockIdx.x * 256 + threadIdx.x;
  if (idx < 4096) bg[idx] = b_ih[idx] + b_hh[idx];
  if (idx < BB * CDIM) {
    int b = idx >> 7, j = idx & 127;
    short hi, lo; split2(cat[idx], hi, lo);
    xh_h[(size_t)b * XHLEN + EE + FF + j] = hi;
    xh_l[(size_t)b * XHLEN + EE + FF + j] = lo;
  }
}

extern "C" void kernel_launch(void* const* d_in, const int* in_sizes, int n_in,
                              void* d_out, int out_size, void* d_ws, size_t ws_size,
                              hipStream_t stream) {
  const int*   captions = (const int*)  d_in[0];
  const float* features = (const float*)d_in[1];
  const float* category = (const float*)d_in[2];
  const float* emb      = (const float*)d_in[3];
  const float* W_ih     = (const float*)d_in[4];
  const float* b_ih     = (const float*)d_in[5];
  const float* W_hh     = (const float*)d_in[6];
  const float* b_hh     = (const float*)d_in[7];
  const float* fc_W     = (const float*)d_in[8];
  const float* fc_b     = (const float*)d_in[9];
  const float* Wh0      = (const float*)d_in[10];
  const float* bh0      = (const float*)d_in[11];
  const float* Wc0      = (const float*)d_in[12];
  const float* bc0      = (const float*)d_in[13];
  const float* att_W    = (const float*)d_in[14];
  const float* att_U    = (const float*)d_in[15];
  const float* att_v    = (const float*)d_in[16];

  float* outs  = (float*)d_out;
  float* w_out = outs + (size_t)BB * TT * VV;

  char* p = (char*)d_ws;
  auto alloc = [&](size_t bytes) {
    char* q = p; p += (bytes + 255) & ~(size_t)255; return q;
  };
  short* attUt = (short*)alloc((size_t)HH * HH * 2);
  short* attWt = (short*)alloc((size_t)HH * FF * 2);
  short* featb = (short*)alloc((size_t)BB * LL * FF * 2);   // prep only; reused as hall
  short* fcWb  = (short*)alloc((size_t)VV * HH * 2);
  short* Wfb   = (short*)alloc((size_t)4096 * XHLEN * 2);
  short* Wh0b  = (short*)alloc((size_t)HH * FF * 2);
  short* Wc0b  = (short*)alloc((size_t)HH * FF * 2);
  short* mfb   = (short*)alloc((size_t)BB * FF * 2);
  short* xh_h  = (short*)alloc((size_t)BB * XHLEN * 2);
  short* xh_l  = (short*)alloc((size_t)BB * XHLEN * 2);
  float* featp = (float*)alloc((size_t)BB * LL * HH * 4);
  float* cbuf  = (float*)alloc((size_t)BB * HH * 4);
  float* partS = (float*)alloc((size_t)BB * 64 * LL * 4);
  float* bg    = (float*)alloc(4096 * 4);
  // h2 history aliases featb (featb dead after the feat_proj prep GEMM).
  short* hall_h = featb;
  short* hall_l = featb + (size_t)TT * BB * HH;

  // ---- one-time prep ----
  transpose_split_k<<<dim3(32, 32), 256, 0, stream>>>(att_U, attUt, HH, HH);
  transpose_split_k<<<dim3(32, 64), 256, 0, stream>>>(att_W, attWt, FF, HH);
  cast_k<<<2048, 256, 0, stream>>>(features, featb, (size_t)BB * LL * FF);
  cast_k<<<2048, 256, 0, stream>>>(fc_W, fcWb, (size_t)VV * HH);
  cast_k<<<1024, 256, 0, stream>>>(Wh0, Wh0b, (size_t)HH * FF);
  cast_k<<<1024, 256, 0, stream>>>(Wc0, Wc0b, (size_t)HH * FF);
  concat_k<<<dim3(15, 4096), 256, 0, stream>>>(W_ih, W_hh, Wfb);
  setup_k<<<32, 256, 0, stream>>>(b_ih, b_hh, bg, category, xh_h, xh_l);
  mean_k<<<512, 256, 0, stream>>>(features, mfb);

  mgemm_k<false, true, 2><<<dim3(32, 1), 256, 0, stream>>>(
      mfb, nullptr, FF, Wh0b, FF, bh0,
      nullptr, 0, xh_h + XKLEN, xh_l + XKLEN, XHLEN, HH, FF);
  mgemm_k<false, false, 2><<<dim3(32, 1), 256, 0, stream>>>(
      mfb, nullptr, FF, Wc0b, FF, bc0,
      cbuf, HH, nullptr, nullptr, 0, HH, FF);
  mgemm_k<false, false, 4><<<dim3(16, 49), 256, 0, stream>>>(
      featb, nullptr, FF, attWt, FF, nullptr,
      featp, HH, nullptr, nullptr, 0, HH, FF);

  // ---- timestep loop: 3 dispatches per step, 128-256 blocks each ----
  for (int t = 0; t < TT; ++t) {
    hupart_k<<<dim3(64, 2), 256, 0, stream>>>(
        xh_h, xh_l, attUt, featp, att_v, partS);
    attn2_k<<<dim3(64, 2), 256, 0, stream>>>(
        partS, features, captions, emb, xh_h, xh_l, w_out, t);
    glstm2_k<<<dim3(64, 4), 256, 0, stream>>>(
        xh_h, xh_l, Wfb, bg, cbuf, xh_h, xh_l, hall_h, hall_l, t);
  }

  // ---- deferred batched fc: LDS-staged 128x128 tiles ----
  bgemm_k<<<dim3(16, 94), 256, 0, stream>>>(hall_h, hall_l, fcWb, fc_b, outs);
}

// Round 13
// 2783.516 us; speedup vs baseline: 17.5793x; 1.2057x over previous
//
#include <hip/hip_runtime.h>
#include <hip/hip_bf16.h>

#define BB 64
#define TT 32
#define VV 12000
#define EE 512
#define FF 2048
#define CDIM 128
#define HH 1024
#define LL 49
#define XKLEN 2688   /* E + F + C */
#define XGLEN 640    /* E + C : per-step gathered input */
#define KGATE 1664   /* XGLEN + HH */

typedef __attribute__((ext_vector_type(8))) short bf16x8;
typedef __attribute__((ext_vector_type(4))) float f32x4;

__device__ __forceinline__ unsigned short bf16_rn(float x) {
  unsigned u = __float_as_uint(x);
  u += 0x7FFFu + ((u >> 16) & 1u);
  return (unsigned short)(u >> 16);
}
__device__ __forceinline__ float bf16_tof(unsigned short h) {
  return __uint_as_float(((unsigned)h) << 16);
}
__device__ __forceinline__ void split2(float x, short& hi, short& lo) {
  unsigned short h = bf16_rn(x);
  float r = x - bf16_tof(h);
  hi = (short)h;
  lo = (short)bf16_rn(r);
}

// ---------------------------------------------------------------------------
// D1: hU tile + partial scores (round-12 proven, h now standalone [64][1024]).
// Grid (64 a-tiles, 2 b-halves) x 256.
// ---------------------------------------------------------------------------
__global__ __launch_bounds__(256) void hupart_k(
    const short* __restrict__ hHi, const short* __restrict__ hLi,
    const short* __restrict__ attUt,   // [1024][1024] bf16 = att_U^T
    const float* __restrict__ featp,   // [B*L][1024] f32
    const float* __restrict__ att_v,
    float* __restrict__ partS)         // [B][64][49]
{
  __shared__ float red[4][64][9];
  __shared__ float hu_s[32][17];
  __shared__ float av_s[16];
  const int tid = threadIdx.x;
  const int w = tid >> 6, lane = tid & 63;
  const int r = lane & 15, kg = lane >> 4;
  const int nt = blockIdx.x, mh = blockIdx.y;
  const int kb = w * 256;

  if (tid < 16) av_s[tid] = att_v[nt * 16 + tid];

  const short* wp  = attUt + (size_t)(nt * 16 + r) * HH + kb + kg * 8;
  const short* ap  = hHi + (size_t)(mh * 32 + r) * HH + kb + kg * 8;
  const short* alp = hLi + (size_t)(mh * 32 + r) * HH + kb + kg * 8;
  f32x4 acc[2] = {};
#pragma unroll
  for (int k0 = 0; k0 < 256; k0 += 32) {
    bf16x8 bf = *(const bf16x8*)(wp + k0);
#pragma unroll
    for (int m = 0; m < 2; ++m) {
      bf16x8 af = *(const bf16x8*)(ap + (size_t)(16 * m) * HH + k0);
      acc[m] = __builtin_amdgcn_mfma_f32_16x16x32_bf16(af, bf, acc[m], 0, 0, 0);
      bf16x8 alf = *(const bf16x8*)(alp + (size_t)(16 * m) * HH + k0);
      acc[m] = __builtin_amdgcn_mfma_f32_16x16x32_bf16(alf, bf, acc[m], 0, 0, 0);
    }
  }
#pragma unroll
  for (int m = 0; m < 2; ++m)
#pragma unroll
    for (int q = 0; q < 4; ++q)
      red[w][lane][m * 4 + q] = acc[m][q];
  __syncthreads();

  for (int idx = tid; idx < 512; idx += 256) {
    const int bl = idx >> 4, a = idx & 15;
    const int m = bl >> 4, wi = bl & 15;
    const int sl = (wi >> 2) * 16 + a;
    const int ii = m * 4 + (wi & 3);
    hu_s[bl][a] = red[0][sl][ii] + red[1][sl][ii] + red[2][sl][ii] + red[3][sl][ii];
  }
  __syncthreads();

  for (int task = tid; task < 32 * LL; task += 256) {
    const int bl = task / LL, l = task - bl * LL;
    const int b = mh * 32 + bl;
    const float* fp = featp + ((size_t)b * LL + l) * HH + nt * 16;
    float s = 0.f;
#pragma unroll
    for (int a = 0; a < 16; ++a)
      s += tanhf(fp[a] + hu_s[bl][a]) * av_s[a];
    partS[((size_t)b * 64 + nt) * LL + l] = s;
  }
}

// ---------------------------------------------------------------------------
// D2: softmax + ctx-weighted-sum + gates MFMA ([xg|h] segments) + LSTM.
// Grid (64 j-tiles, 4 b-quarters) x 256. Writes h into hall[t] (ping-pong).
// ---------------------------------------------------------------------------
__global__ __launch_bounds__(256) void glstm3_k(
    const short* __restrict__ xgH, const short* __restrict__ xgL,  // [2048][640]
    const short* __restrict__ hHi, const short* __restrict__ hLi,  // [64][1024] = h(t-1)
    const short* __restrict__ Wxg,      // [4096][640]
    const short* __restrict__ Whb,      // [4096][1024]
    const short* __restrict__ featCtx,  // [3136][4096] bf16
    const float* __restrict__ partS,    // [64][64][49]
    const float* __restrict__ bg,
    float* __restrict__ cbuf,
    short* __restrict__ hHo, short* __restrict__ hLo,  // h(t) out (hall slot t)
    float* __restrict__ w_out, int t)
{
  __shared__ float sw[16][52];
  __shared__ float ctx_s[16][68];
  __shared__ float red[3][64][17];
  const int tid = threadIdx.x;
  const int w = tid >> 6, lane = tid & 63;
  const int r = lane & 15, kg = lane >> 4;
  const int nt = blockIdx.x, mq = blockIdx.y;

  // Phase A: raw scores for this block's 16 b's
  for (int idx = tid; idx < 16 * LL; idx += 256) {
    const int bl = idx / LL, l = idx - bl * LL;
    const int b = mq * 16 + bl;
    const float* ps = partS + ((size_t)b * 64) * LL + l;
    float s = 0.f;
#pragma unroll 8
    for (int a = 0; a < 64; ++a) s += ps[a * LL];
    sw[bl][l] = s;
  }
  __syncthreads();
  // softmax: wave w handles b_loc = w*4 .. +3
#pragma unroll
  for (int i = 0; i < 4; ++i) {
    const int bl = w * 4 + i;
    float v = (lane < LL) ? sw[bl][lane] : -1e30f;
    float m = v;
#pragma unroll
    for (int off = 32; off > 0; off >>= 1) m = fmaxf(m, __shfl_xor(m, off));
    float e = (lane < LL) ? expf(v - m) : 0.f;
    float s = e;
#pragma unroll
    for (int off = 32; off > 0; off >>= 1) s += __shfl_xor(s, off);
    float ww = e / s;
    if (lane < LL) {
      sw[bl][lane] = ww;
      if (nt == 0)
        w_out[((size_t)(mq * 16 + bl) * TT + t) * LL + lane] = ww;
    }
  }
  __syncthreads();

  // Phase B: ctx_s[bl][gate*16 + j] = sum_l w[bl][l] * featCtx[(b*49+l)][gate*1024+nt*16+j]
  {
    const int bl = tid >> 4, sub = tid & 15;
    const int gate = sub >> 2, j4 = (sub & 3) * 4;
    const int bglob = mq * 16 + bl;
    const size_t base = ((size_t)bglob * LL) * 4096 + gate * 1024 + nt * 16 + j4;
    float s0 = 0.f, s1 = 0.f, s2 = 0.f, s3 = 0.f;
#pragma unroll
    for (int l = 0; l < LL; ++l) {
      short4 v = *(const short4*)&featCtx[base + (size_t)l * 4096];
      const float wl = sw[bl][l];
      s0 += wl * bf16_tof((unsigned short)v.x);
      s1 += wl * bf16_tof((unsigned short)v.y);
      s2 += wl * bf16_tof((unsigned short)v.z);
      s3 += wl * bf16_tof((unsigned short)v.w);
    }
    ctx_s[bl][gate * 16 + j4 + 0] = s0;
    ctx_s[bl][gate * 16 + j4 + 1] = s1;
    ctx_s[bl][gate * 16 + j4 + 2] = s2;
    ctx_s[bl][gate * 16 + j4 + 3] = s3;
  }

  // Phase C: gates MFMA over [xg(640) | h(1024)], K split 4 waves x 13 chunks
  const int brow = mq * 16 + r;
  const size_t xgrow = (size_t)t * 64 + brow;
  f32x4 acc0 = {}, acc1 = {}, acc2 = {}, acc3 = {};
#pragma unroll
  for (int c = 0; c < 13; ++c) {
    const int gk = (w * 13 + c) * 32;
    const short *a_h, *a_l, *w0p, *w1p, *w2p, *w3p;
    if (gk < XGLEN) {
      a_h = xgH + xgrow * XGLEN + gk + kg * 8;
      a_l = xgL + xgrow * XGLEN + gk + kg * 8;
      w0p = Wxg + (size_t)(0 * 1024 + nt * 16 + r) * XGLEN + gk + kg * 8;
      w1p = Wxg + (size_t)(1 * 1024 + nt * 16 + r) * XGLEN + gk + kg * 8;
      w2p = Wxg + (size_t)(2 * 1024 + nt * 16 + r) * XGLEN + gk + kg * 8;
      w3p = Wxg + (size_t)(3 * 1024 + nt * 16 + r) * XGLEN + gk + kg * 8;
    } else {
      const int hk = gk - XGLEN;
      a_h = hHi + (size_t)brow * HH + hk + kg * 8;
      a_l = hLi + (size_t)brow * HH + hk + kg * 8;
      w0p = Whb + (size_t)(0 * 1024 + nt * 16 + r) * HH + hk + kg * 8;
      w1p = Whb + (size_t)(1 * 1024 + nt * 16 + r) * HH + hk + kg * 8;
      w2p = Whb + (size_t)(2 * 1024 + nt * 16 + r) * HH + hk + kg * 8;
      w3p = Whb + (size_t)(3 * 1024 + nt * 16 + r) * HH + hk + kg * 8;
    }
    bf16x8 af  = *(const bf16x8*)a_h;
    bf16x8 alf = *(const bf16x8*)a_l;
    bf16x8 b0 = *(const bf16x8*)w0p;
    acc0 = __builtin_amdgcn_mfma_f32_16x16x32_bf16(af,  b0, acc0, 0, 0, 0);
    acc0 = __builtin_amdgcn_mfma_f32_16x16x32_bf16(alf, b0, acc0, 0, 0, 0);
    bf16x8 b1 = *(const bf16x8*)w1p;
    acc1 = __builtin_amdgcn_mfma_f32_16x16x32_bf16(af,  b1, acc1, 0, 0, 0);
    acc1 = __builtin_amdgcn_mfma_f32_16x16x32_bf16(alf, b1, acc1, 0, 0, 0);
    bf16x8 b2 = *(const bf16x8*)w2p;
    acc2 = __builtin_amdgcn_mfma_f32_16x16x32_bf16(af,  b2, acc2, 0, 0, 0);
    acc2 = __builtin_amdgcn_mfma_f32_16x16x32_bf16(alf, b2, acc2, 0, 0, 0);
    bf16x8 b3 = *(const bf16x8*)w3p;
    acc3 = __builtin_amdgcn_mfma_f32_16x16x32_bf16(af,  b3, acc3, 0, 0, 0);
    acc3 = __builtin_amdgcn_mfma_f32_16x16x32_bf16(alf, b3, acc3, 0, 0, 0);
  }

  if (w != 0) {
#pragma unroll
    for (int q = 0; q < 4; ++q) {
      red[w - 1][lane][0 * 4 + q] = acc0[q];
      red[w - 1][lane][1 * 4 + q] = acc1[q];
      red[w - 1][lane][2 * 4 + q] = acc2[q];
      red[w - 1][lane][3 * 4 + q] = acc3[q];
    }
  }
  __syncthreads();
  if (w == 0) {
    const int j = nt * 16 + r;
    const float b0 = bg[j], b1 = bg[1024 + j], b2 = bg[2048 + j], b3 = bg[3072 + j];
#pragma unroll
    for (int q = 0; q < 4; ++q) {
      const int bl = kg * 4 + q;
      float gi = acc0[q] + b0 + ctx_s[bl][0 * 16 + r];
      float gf = acc1[q] + b1 + ctx_s[bl][1 * 16 + r];
      float gg = acc2[q] + b2 + ctx_s[bl][2 * 16 + r];
      float go = acc3[q] + b3 + ctx_s[bl][3 * 16 + r];
#pragma unroll
      for (int p = 0; p < 3; ++p) {
        gi += red[p][lane][0 * 4 + q];
        gf += red[p][lane][1 * 4 + q];
        gg += red[p][lane][2 * 4 + q];
        go += red[p][lane][3 * 4 + q];
      }
      const int b = mq * 16 + bl;
      float si = 1.f / (1.f + expf(-gi));
      float sf = 1.f / (1.f + expf(-gf));
      float so = 1.f / (1.f + expf(-go));
      const size_t ci = (size_t)b * HH + j;
      float cc = sf * cbuf[ci] + si * tanhf(gg);
      float hh = so * tanhf(cc);
      cbuf[ci] = cc;
      short hi, lo; split2(hh, hi, lo);
      hHo[ci] = hi;
      hLo[ci] = lo;
    }
  }
}

// ---------------------------------------------------------------------------
// Generic LDS-tiled GEMM (single-pass A): out[M,N] = A[M,K] @ W[N,K]^T.
// 128x128 tile, BK=32, padded LDS. Template: bf16 or f32 output.
// Grid (ceil(M/128), N/128) x-major => consecutive blocks share W panel.
// ---------------------------------------------------------------------------
template<bool BF16OUT>
__global__ __launch_bounds__(256) void tgemm_k(
    const short* __restrict__ A, const short* __restrict__ Wb,
    float* __restrict__ outf, short* __restrict__ outb,
    int M, int N, int K, int ldo)
{
  __shared__ short lA[128 * 40];
  __shared__ short lW[128 * 40];
  const int tid = threadIdx.x;
  const int w = tid >> 6, lane = tid & 63;
  const int r = lane & 15, kg = lane >> 4;
  const int m0 = blockIdx.x * 128;
  const int n0 = blockIdx.y * 128;
  const int srow = tid >> 2, scol = (tid & 3) * 8;

  f32x4 acc[2][8] = {};
  for (int k0 = 0; k0 < K; k0 += 32) {
    __syncthreads();
#pragma unroll
    for (int j = 0; j < 2; ++j) {
      const int row = j * 64 + srow;
      int ar = m0 + row; if (ar >= M) ar = M - 1;
      int wr = n0 + row; if (wr >= N) wr = N - 1;
      bf16x8 va = *(const bf16x8*)&A[(size_t)ar * K + k0 + scol];
      bf16x8 vw = *(const bf16x8*)&Wb[(size_t)wr * K + k0 + scol];
      *(bf16x8*)&lA[row * 40 + scol] = va;
      *(bf16x8*)&lW[row * 40 + scol] = vw;
    }
    __syncthreads();
    bf16x8 a0 = *(const bf16x8*)&lA[(w * 32 +  0 + r) * 40 + kg * 8];
    bf16x8 a1 = *(const bf16x8*)&lA[(w * 32 + 16 + r) * 40 + kg * 8];
#pragma unroll
    for (int nf = 0; nf < 8; ++nf) {
      bf16x8 wf = *(const bf16x8*)&lW[(nf * 16 + r) * 40 + kg * 8];
      acc[0][nf] = __builtin_amdgcn_mfma_f32_16x16x32_bf16(a0, wf, acc[0][nf], 0, 0, 0);
      acc[1][nf] = __builtin_amdgcn_mfma_f32_16x16x32_bf16(a1, wf, acc[1][nf], 0, 0, 0);
    }
  }
#pragma unroll
  for (int nf = 0; nf < 8; ++nf) {
    const int col = n0 + nf * 16 + r;
    if (col < N) {
#pragma unroll
      for (int mf = 0; mf < 2; ++mf)
#pragma unroll
        for (int q = 0; q < 4; ++q) {
          const int grow = m0 + w * 32 + mf * 16 + kg * 4 + q;
          if (grow < M) {
            if (BF16OUT) outb[(size_t)grow * ldo + col] = (short)bf16_rn(acc[mf][nf][q]);
            else         outf[(size_t)grow * ldo + col] = acc[mf][nf][q];
          }
        }
    }
  }
}

// ---------------------------------------------------------------------------
// Batched fc GEMM, LDS-staged 128x128 tile (round-10 proven). Grid (16, 94).
// ---------------------------------------------------------------------------
__global__ __launch_bounds__(256) void bgemm_k(
    const short* __restrict__ Ah, const short* __restrict__ Al,
    const short* __restrict__ Wb, const float* __restrict__ bias,
    float* __restrict__ outs)
{
  __shared__ short lAh[128 * 40];
  __shared__ short lAl[128 * 40];
  __shared__ short lW [128 * 40];
  const int tid = threadIdx.x;
  const int w = tid >> 6, lane = tid & 63;
  const int r = lane & 15, kg = lane >> 4;
  const int m0 = blockIdx.x * 128;
  const int n0 = blockIdx.y * 128;
  const int srow = tid >> 2, scol = (tid & 3) * 8;

  f32x4 acc[2][8] = {};
  for (int k0 = 0; k0 < HH; k0 += 32) {
    __syncthreads();
#pragma unroll
    for (int j = 0; j < 2; ++j) {
      const int row = j * 64 + srow;
      bf16x8 va = *(const bf16x8*)&Ah[(size_t)(m0 + row) * HH + k0 + scol];
      bf16x8 vl = *(const bf16x8*)&Al[(size_t)(m0 + row) * HH + k0 + scol];
      int wr = n0 + row; if (wr >= VV) wr = VV - 1;
      bf16x8 vw = *(const bf16x8*)&Wb[(size_t)wr * HH + k0 + scol];
      *(bf16x8*)&lAh[row * 40 + scol] = va;
      *(bf16x8*)&lAl[row * 40 + scol] = vl;
      *(bf16x8*)&lW [row * 40 + scol] = vw;
    }
    __syncthreads();
    bf16x8 ah0 = *(const bf16x8*)&lAh[(w * 32 +  0 + r) * 40 + kg * 8];
    bf16x8 ah1 = *(const bf16x8*)&lAh[(w * 32 + 16 + r) * 40 + kg * 8];
    bf16x8 al0 = *(const bf16x8*)&lAl[(w * 32 +  0 + r) * 40 + kg * 8];
    bf16x8 al1 = *(const bf16x8*)&lAl[(w * 32 + 16 + r) * 40 + kg * 8];
#pragma unroll
    for (int nf = 0; nf < 8; ++nf) {
      bf16x8 wf = *(const bf16x8*)&lW[(nf * 16 + r) * 40 + kg * 8];
      acc[0][nf] = __builtin_amdgcn_mfma_f32_16x16x32_bf16(ah0, wf, acc[0][nf], 0, 0, 0);
      acc[0][nf] = __builtin_amdgcn_mfma_f32_16x16x32_bf16(al0, wf, acc[0][nf], 0, 0, 0);
      acc[1][nf] = __builtin_amdgcn_mfma_f32_16x16x32_bf16(ah1, wf, acc[1][nf], 0, 0, 0);
      acc[1][nf] = __builtin_amdgcn_mfma_f32_16x16x32_bf16(al1, wf, acc[1][nf], 0, 0, 0);
    }
  }
#pragma unroll
  for (int nf = 0; nf < 8; ++nf) {
    const int colv = n0 + nf * 16 + r;
    if (colv < VV) {
      const float bv = bias[colv];
#pragma unroll
      for (int mf = 0; mf < 2; ++mf)
#pragma unroll
        for (int q = 0; q < 4; ++q) {
          const int grow = m0 + w * 32 + mf * 16 + kg * 4 + q;  // = t*64 + b
          const int tt = grow >> 6, b = grow & 63;
          outs[((size_t)b * TT + tt) * VV + colv] = acc[mf][nf][q] + bv;
        }
    }
  }
}

// ---------------------------------------------------------------------------
// MFMA GEMM used in one-time prep (h0, c0).
// ---------------------------------------------------------------------------
template<bool TWOPASS, bool SPLITOUT, int MT>
__global__ __launch_bounds__(256) void mgemm_k(
    const short* __restrict__ Ah, const short* __restrict__ Al, int lda,
    const short* __restrict__ Wb, int ldw,
    const float* __restrict__ bias,
    float* __restrict__ C, int ldc,
    short* __restrict__ Ch, short* __restrict__ Cl, int ldch,
    int N, int K)
{
  const int tid = threadIdx.x;
  const int w = tid >> 6, l = tid & 63;
  const int r = l & 15, kg = l >> 4;
  const int m0 = blockIdx.y * 64;
  const int nslice = (MT == 4) ? w : (w >> 1);
  const int mbase  = (MT == 4) ? 0 : ((w & 1) * 2);
  const int n0 = blockIdx.x * (MT * 16) + nslice * 16;
  const int nrow = n0 + r;
  const int nclmp = nrow < N ? nrow : N - 1;
  const short* wp  = Wb + (size_t)nclmp * ldw + kg * 8;
  const short* ap  = Ah + (size_t)(m0 + mbase * 16 + r) * lda + kg * 8;
  const short* alp = TWOPASS ? (Al + (size_t)(m0 + mbase * 16 + r) * lda + kg * 8)
                             : nullptr;
  f32x4 acc[MT] = {};
  for (int k0 = 0; k0 < K; k0 += 32) {
    bf16x8 bf = *(const bf16x8*)(wp + k0);
#pragma unroll
    for (int m = 0; m < MT; ++m) {
      bf16x8 af = *(const bf16x8*)(ap + (size_t)(16 * m) * lda + k0);
      acc[m] = __builtin_amdgcn_mfma_f32_16x16x32_bf16(af, bf, acc[m], 0, 0, 0);
      if (TWOPASS) {
        bf16x8 alf = *(const bf16x8*)(alp + (size_t)(16 * m) * lda + k0);
        acc[m] = __builtin_amdgcn_mfma_f32_16x16x32_bf16(alf, bf, acc[m], 0, 0, 0);
      }
    }
  }
  if (nrow < N) {
    float bv = bias ? bias[nrow] : 0.f;
#pragma unroll
    for (int m = 0; m < MT; ++m) {
#pragma unroll
      for (int q = 0; q < 4; ++q) {
        int mm = m0 + (mbase + m) * 16 + kg * 4 + q;
        float v = acc[m][q] + bv;
        if (SPLITOUT) {
          short hi, lo; split2(v, hi, lo);
          Ch[(size_t)mm * ldch + nrow] = hi;
          Cl[(size_t)mm * ldch + nrow] = lo;
        } else {
          C[(size_t)mm * ldc + nrow] = v;
        }
      }
    }
  }
}

__global__ __launch_bounds__(256) void transpose_split_k(
    const float* __restrict__ in, short* __restrict__ out, int R, int C)
{
  __shared__ float tile[32][33];
  int bc = blockIdx.x * 32, br = blockIdx.y * 32;
  int tx = threadIdx.x & 31, ty4 = (threadIdx.x >> 5) << 2;
#pragma unroll
  for (int i = 0; i < 4; ++i) {
    int r = br + ty4 + i, c = bc + tx;
    tile[ty4 + i][tx] = (r < R && c < C) ? in[(size_t)r * C + c] : 0.f;
  }
  __syncthreads();
#pragma unroll
  for (int i = 0; i < 4; ++i) {
    int oc = bc + ty4 + i, orr = br + tx;
    if (oc < C && orr < R) out[(size_t)oc * R + orr] = (short)bf16_rn(tile[tx][ty4 + i]);
  }
}

__global__ __launch_bounds__(256) void cast_k(
    const float* __restrict__ in, short* __restrict__ out, size_t n)
{
  for (size_t i = blockIdx.x * 256ULL + threadIdx.x; i < n; i += gridDim.x * 256ULL)
    out[i] = (short)bf16_rn(in[i]);
}

// Wxg[n][k] = bf16(W_ih[n][ k<512 ? k : EE+FF+(k-512) ])  (emb|cat cols)
__global__ __launch_bounds__(256) void wxg_k(const float* __restrict__ wih,
                                             short* __restrict__ out)
{
  for (size_t i = blockIdx.x * 256ULL + threadIdx.x; i < (size_t)4096 * XGLEN;
       i += gridDim.x * 256ULL) {
    const int n = i / XGLEN, k = i % XGLEN;
    const int ks = (k < EE) ? k : (EE + FF + (k - EE));
    out[i] = (short)bf16_rn(wih[(size_t)n * XKLEN + ks]);
  }
}

// Wctxb[n][k] = bf16(W_ih[n][EE + k]), k < 2048
__global__ __launch_bounds__(256) void wctx_k(const float* __restrict__ wih,
                                              short* __restrict__ out)
{
  for (size_t i = blockIdx.x * 256ULL + threadIdx.x; i < (size_t)4096 * FF;
       i += gridDim.x * 256ULL) {
    const int n = i / FF, k = i % FF;
    out[i] = (short)bf16_rn(wih[(size_t)n * XKLEN + EE + k]);
  }
}

// xg[t*64+b][0:512] = emb[cap[b][t]]; [512:640] = category[b]  (hi/lo split)
__global__ __launch_bounds__(256) void xg_k(
    const int* __restrict__ captions, const float* __restrict__ emb,
    const float* __restrict__ cat,
    short* __restrict__ xgH, short* __restrict__ xgL)
{
  for (size_t i = blockIdx.x * 256ULL + threadIdx.x; i < (size_t)2048 * XGLEN;
       i += gridDim.x * 256ULL) {
    const int row = i / XGLEN, k = i % XGLEN;
    const int t = row >> 6, b = row & 63;
    float v;
    if (k < EE) {
      const int cap = captions[b * TT + t];
      v = emb[(size_t)cap * EE + k];
    } else {
      v = cat[(size_t)b * CDIM + (k - EE)];
    }
    short hi, lo; split2(v, hi, lo);
    xgH[i] = hi;
    xgL[i] = lo;
  }
}

__global__ __launch_bounds__(256) void mean_k(
    const float* __restrict__ feat, short* __restrict__ mf)
{
  int idx = blockIdx.x * 256 + threadIdx.x;
  int b = idx >> 11, f = idx & 2047;
  float s = 0.f;
#pragma unroll
  for (int l = 0; l < LL; ++l) s += feat[((size_t)b * LL + l) * FF + f];
  mf[idx] = (short)bf16_rn(s * (1.f / 49.f));
}

__global__ __launch_bounds__(256) void setup_k(
    const float* __restrict__ b_ih, const float* __restrict__ b_hh,
    float* __restrict__ bg)
{
  int idx = blockIdx.x * 256 + threadIdx.x;
  if (idx < 4096) bg[idx] = b_ih[idx] + b_hh[idx];
}

extern "C" void kernel_launch(void* const* d_in, const int* in_sizes, int n_in,
                              void* d_out, int out_size, void* d_ws, size_t ws_size,
                              hipStream_t stream) {
  const int*   captions = (const int*)  d_in[0];
  const float* features = (const float*)d_in[1];
  const float* category = (const float*)d_in[2];
  const float* emb      = (const float*)d_in[3];
  const float* W_ih     = (const float*)d_in[4];
  const float* b_ih     = (const float*)d_in[5];
  const float* W_hh     = (const float*)d_in[6];
  const float* b_hh     = (const float*)d_in[7];
  const float* fc_W     = (const float*)d_in[8];
  const float* fc_b     = (const float*)d_in[9];
  const float* Wh0      = (const float*)d_in[10];
  const float* bh0      = (const float*)d_in[11];
  const float* Wc0      = (const float*)d_in[12];
  const float* bc0      = (const float*)d_in[13];
  const float* att_W    = (const float*)d_in[14];
  const float* att_U    = (const float*)d_in[15];
  const float* att_v    = (const float*)d_in[16];

  float* outs  = (float*)d_out;
  float* w_out = outs + (size_t)BB * TT * VV;

  char* p = (char*)d_ws;
  auto alloc = [&](size_t bytes) {
    char* q = p; p += (bytes + 255) & ~(size_t)255; return q;
  };
  short* attUt  = (short*)alloc((size_t)HH * HH * 2);
  short* attWt  = (short*)alloc((size_t)HH * FF * 2);
  short* featb  = (short*)alloc((size_t)BB * LL * FF * 2);   // prep only; reused as hall
  short* fcWb   = (short*)alloc((size_t)VV * HH * 2);
  short* Wctxb  = (short*)alloc((size_t)4096 * FF * 2);
  short* Whb    = (short*)alloc((size_t)4096 * HH * 2);
  short* Wxg    = (short*)alloc((size_t)4096 * XGLEN * 2);
  short* Wh0b   = (short*)alloc((size_t)HH * FF * 2);
  short* Wc0b   = (short*)alloc((size_t)HH * FF * 2);
  short* mfb    = (short*)alloc((size_t)BB * FF * 2);
  short* h0H    = (short*)alloc((size_t)BB * HH * 2);
  short* h0L    = (short*)alloc((size_t)BB * HH * 2);
  short* xgH    = (short*)alloc((size_t)2048 * XGLEN * 2);
  short* xgL    = (short*)alloc((size_t)2048 * XGLEN * 2);
  float* featp  = (float*)alloc((size_t)BB * LL * HH * 4);
  short* featCtx= (short*)alloc((size_t)BB * LL * 4096 * 2);
  float* cbuf   = (float*)alloc((size_t)BB * HH * 4);
  float* partS  = (float*)alloc((size_t)BB * 64 * LL * 4);
  float* bg     = (float*)alloc(4096 * 4);
  // h history (= h(t) for t=0..31) aliases featb (dead after prep GEMMs).
  short* hallH = featb;
  short* hallL = featb + (size_t)TT * BB * HH;

  // ---- one-time prep ----
  transpose_split_k<<<dim3(32, 32), 256, 0, stream>>>(att_U, attUt, HH, HH);
  transpose_split_k<<<dim3(32, 64), 256, 0, stream>>>(att_W, attWt, FF, HH);
  cast_k<<<2048, 256, 0, stream>>>(features, featb, (size_t)BB * LL * FF);
  cast_k<<<2048, 256, 0, stream>>>(fc_W, fcWb, (size_t)VV * HH);
  cast_k<<<1024, 256, 0, stream>>>(Wh0, Wh0b, (size_t)HH * FF);
  cast_k<<<1024, 256, 0, stream>>>(Wc0, Wc0b, (size_t)HH * FF);
  cast_k<<<1024, 256, 0, stream>>>(W_hh, Whb, (size_t)4096 * HH);
  wxg_k<<<2048, 256, 0, stream>>>(W_ih, Wxg);
  wctx_k<<<4096, 256, 0, stream>>>(W_ih, Wctxb);
  xg_k<<<2048, 256, 0, stream>>>(captions, emb, category, xgH, xgL);
  setup_k<<<16, 256, 0, stream>>>(b_ih, b_hh, bg);
  mean_k<<<512, 256, 0, stream>>>(features, mfb);

  // h0 / c0
  mgemm_k<false, true, 2><<<dim3(32, 1), 256, 0, stream>>>(
      mfb, nullptr, FF, Wh0b, FF, bh0,
      nullptr, 0, h0H, h0L, HH, HH, FF);
  mgemm_k<false, false, 2><<<dim3(32, 1), 256, 0, stream>>>(
      mfb, nullptr, FF, Wc0b, FF, bc0,
      cbuf, HH, nullptr, nullptr, 0, HH, FF);
  // featp = features @ att_W   (fp32 out, [3136][1024])
  tgemm_k<false><<<dim3(25, 8), 256, 0, stream>>>(
      featb, attWt, featp, nullptr, BB * LL, HH, FF, HH);
  // featCtx = features @ W_ih_ctx^T  (bf16 out, [3136][4096])
  tgemm_k<true><<<dim3(25, 32), 256, 0, stream>>>(
      featb, Wctxb, nullptr, featCtx, BB * LL, 4096, FF, 4096);

  // ---- timestep loop: 2 dispatches per step ----
  for (int t = 0; t < TT; ++t) {
    const short* hHi = (t == 0) ? h0H : hallH + (size_t)(t - 1) * BB * HH;
    const short* hLi = (t == 0) ? h0L : hallL + (size_t)(t - 1) * BB * HH;
    hupart_k<<<dim3(64, 2), 256, 0, stream>>>(
        hHi, hLi, attUt, featp, att_v, partS);
    glstm3_k<<<dim3(64, 4), 256, 0, stream>>>(
        xgH, xgL, hHi, hLi, Wxg, Whb, featCtx, partS, bg, cbuf,
        hallH + (size_t)t * BB * HH, hallL + (size_t)t * BB * HH, w_out, t);
  }

  // ---- deferred batched fc ----
  bgemm_k<<<dim3(16, 94), 256, 0, stream>>>(hallH, hallL, fcWb, fc_b, outs);
}

// Round 14
// 2510.857 us; speedup vs baseline: 19.4882x; 1.1086x over previous
//
#include <hip/hip_runtime.h>
#include <hip/hip_bf16.h>

#define BB 64
#define TT 32
#define VV 12000
#define EE 512
#define FF 2048
#define CDIM 128
#define HH 1024
#define LL 49
#define XKLEN 2688   /* E + F + C */
#define XGLEN 640    /* E + C : per-step gathered input */

typedef __attribute__((ext_vector_type(8))) short bf16x8;
typedef __attribute__((ext_vector_type(4))) float f32x4;

__device__ __forceinline__ unsigned short bf16_rn(float x) {
  unsigned u = __float_as_uint(x);
  u += 0x7FFFu + ((u >> 16) & 1u);
  return (unsigned short)(u >> 16);
}
__device__ __forceinline__ float bf16_tof(unsigned short h) {
  return __uint_as_float(((unsigned)h) << 16);
}
__device__ __forceinline__ void split2(float x, short& hi, short& lo) {
  unsigned short h = bf16_rn(x);
  float r = x - bf16_tof(h);
  hi = (short)h;
  lo = (short)bf16_rn(r);
}

// ---------------------------------------------------------------------------
// D1: hU tile + partial scores. Grid (64 a-tiles, 2 b-halves) x 256.
// partS layout: [nt][b][l]  (nt-major -> contiguous per-block writes)
// ---------------------------------------------------------------------------
__global__ __launch_bounds__(256) void hupart_k(
    const short* __restrict__ hHi, const short* __restrict__ hLi,
    const short* __restrict__ attUt,   // [1024][1024] bf16 = att_U^T
    const float* __restrict__ featp,   // [B*L][1024] f32
    const float* __restrict__ att_v,
    float* __restrict__ partS)         // [64 nt][64 b][49 l]
{
  __shared__ float red[4][64][9];
  __shared__ float hu_s[32][17];
  __shared__ float av_s[16];
  const int tid = threadIdx.x;
  const int w = tid >> 6, lane = tid & 63;
  const int r = lane & 15, kg = lane >> 4;
  const int nt = blockIdx.x, mh = blockIdx.y;
  const int kb = w * 256;

  if (tid < 16) av_s[tid] = att_v[nt * 16 + tid];

  const short* wp  = attUt + (size_t)(nt * 16 + r) * HH + kb + kg * 8;
  const short* ap  = hHi + (size_t)(mh * 32 + r) * HH + kb + kg * 8;
  const short* alp = hLi + (size_t)(mh * 32 + r) * HH + kb + kg * 8;
  f32x4 acc[2] = {};
#pragma unroll
  for (int k0 = 0; k0 < 256; k0 += 32) {
    bf16x8 bf = *(const bf16x8*)(wp + k0);
#pragma unroll
    for (int m = 0; m < 2; ++m) {
      bf16x8 af = *(const bf16x8*)(ap + (size_t)(16 * m) * HH + k0);
      acc[m] = __builtin_amdgcn_mfma_f32_16x16x32_bf16(af, bf, acc[m], 0, 0, 0);
      bf16x8 alf = *(const bf16x8*)(alp + (size_t)(16 * m) * HH + k0);
      acc[m] = __builtin_amdgcn_mfma_f32_16x16x32_bf16(alf, bf, acc[m], 0, 0, 0);
    }
  }
#pragma unroll
  for (int m = 0; m < 2; ++m)
#pragma unroll
    for (int q = 0; q < 4; ++q)
      red[w][lane][m * 4 + q] = acc[m][q];
  __syncthreads();

  for (int idx = tid; idx < 512; idx += 256) {
    const int bl = idx >> 4, a = idx & 15;
    const int m = bl >> 4, wi = bl & 15;
    const int sl = (wi >> 2) * 16 + a;
    const int ii = m * 4 + (wi & 3);
    hu_s[bl][a] = red[0][sl][ii] + red[1][sl][ii] + red[2][sl][ii] + red[3][sl][ii];
  }
  __syncthreads();

  for (int task = tid; task < 32 * LL; task += 256) {
    const int bl = task / LL, l = task - bl * LL;
    const int b = mh * 32 + bl;
    const float* fp = featp + ((size_t)b * LL + l) * HH + nt * 16;
    float s = 0.f;
#pragma unroll
    for (int a = 0; a < 16; ++a)
      s += tanhf(fp[a] + hu_s[bl][a]) * av_s[a];
    // [nt][b][l] with b*49+l = mh*1568 + task  -> contiguous in task
    partS[(size_t)nt * 3136 + (size_t)mh * 1568 + task] = s;
  }
}

// ---------------------------------------------------------------------------
// D2: softmax + ctx-weighted-sum + gates MFMA ([xg|h] segments) + LSTM.
// Grid (64 j-tiles, 4 b-quarters) x 256. Writes h into hall[t] (ping-pong).
// featCtx layout: [nt][3136][64]  (dense per-block reads)
// ---------------------------------------------------------------------------
__global__ __launch_bounds__(256) void glstm3_k(
    const short* __restrict__ xgH, const short* __restrict__ xgL,  // [2048][640]
    const short* __restrict__ hHi, const short* __restrict__ hLi,  // [64][1024] = h(t-1)
    const short* __restrict__ Wxg,      // [4096][640]
    const short* __restrict__ Whb,      // [4096][1024]
    const short* __restrict__ featCtx,  // [64][3136][64] bf16
    const float* __restrict__ partS,    // [64 nt][64 b][49 l]
    const float* __restrict__ bg,
    float* __restrict__ cbuf,
    short* __restrict__ hHo, short* __restrict__ hLo,  // h(t) out (hall slot t)
    float* __restrict__ w_out, int t)
{
  __shared__ float sw[16][52];
  __shared__ float ctx_s[16][68];
  __shared__ float red[3][64][17];
  const int tid = threadIdx.x;
  const int w = tid >> 6, lane = tid & 63;
  const int r = lane & 15, kg = lane >> 4;
  const int nt = blockIdx.x, mq = blockIdx.y;

  // Phase A: raw scores for this block's 16 b's (coalesced nt-major reads)
  for (int idx = tid; idx < 16 * LL; idx += 256) {
    const float* ps = partS + (size_t)mq * 784 + idx;
    float s = 0.f;
#pragma unroll 8
    for (int a = 0; a < 64; ++a) s += ps[(size_t)a * 3136];
    sw[idx / LL][idx % LL] = s;
  }
  __syncthreads();
  // softmax: wave w handles b_loc = w*4 .. +3
#pragma unroll
  for (int i = 0; i < 4; ++i) {
    const int bl = w * 4 + i;
    float v = (lane < LL) ? sw[bl][lane] : -1e30f;
    float m = v;
#pragma unroll
    for (int off = 32; off > 0; off >>= 1) m = fmaxf(m, __shfl_xor(m, off));
    float e = (lane < LL) ? expf(v - m) : 0.f;
    float s = e;
#pragma unroll
    for (int off = 32; off > 0; off >>= 1) s += __shfl_xor(s, off);
    float ww = e / s;
    if (lane < LL) {
      sw[bl][lane] = ww;
      if (nt == 0)
        w_out[((size_t)(mq * 16 + bl) * TT + t) * LL + lane] = ww;
    }
  }
  __syncthreads();

  // Phase B: ctx_s[bl][e] = sum_l w[bl][l] * featCtx[nt][(b*49+l)][e], e=gate*16+j
  {
    const int bl = tid >> 4, e4 = (tid & 15) * 4;
    const size_t base =
        ((size_t)nt * 3136 + (size_t)(mq * 16 + bl) * LL) * 64 + e4;
    float s0 = 0.f, s1 = 0.f, s2 = 0.f, s3 = 0.f;
#pragma unroll
    for (int l = 0; l < LL; ++l) {
      short4 v = *(const short4*)&featCtx[base + (size_t)l * 64];
      const float wl = sw[bl][l];
      s0 += wl * bf16_tof((unsigned short)v.x);
      s1 += wl * bf16_tof((unsigned short)v.y);
      s2 += wl * bf16_tof((unsigned short)v.z);
      s3 += wl * bf16_tof((unsigned short)v.w);
    }
    ctx_s[bl][e4 + 0] = s0;
    ctx_s[bl][e4 + 1] = s1;
    ctx_s[bl][e4 + 2] = s2;
    ctx_s[bl][e4 + 3] = s3;
  }

  // Phase C: gates MFMA over [xg(640) | h(1024)], K split 4 waves x 13 chunks
  const int brow = mq * 16 + r;
  const size_t xgrow = (size_t)t * 64 + brow;
  f32x4 acc0 = {}, acc1 = {}, acc2 = {}, acc3 = {};
#pragma unroll
  for (int c = 0; c < 13; ++c) {
    const int gk = (w * 13 + c) * 32;
    const short *a_h, *a_l, *w0p, *w1p, *w2p, *w3p;
    if (gk < XGLEN) {
      a_h = xgH + xgrow * XGLEN + gk + kg * 8;
      a_l = xgL + xgrow * XGLEN + gk + kg * 8;
      w0p = Wxg + (size_t)(0 * 1024 + nt * 16 + r) * XGLEN + gk + kg * 8;
      w1p = Wxg + (size_t)(1 * 1024 + nt * 16 + r) * XGLEN + gk + kg * 8;
      w2p = Wxg + (size_t)(2 * 1024 + nt * 16 + r) * XGLEN + gk + kg * 8;
      w3p = Wxg + (size_t)(3 * 1024 + nt * 16 + r) * XGLEN + gk + kg * 8;
    } else {
      const int hk = gk - XGLEN;
      a_h = hHi + (size_t)brow * HH + hk + kg * 8;
      a_l = hLi + (size_t)brow * HH + hk + kg * 8;
      w0p = Whb + (size_t)(0 * 1024 + nt * 16 + r) * HH + hk + kg * 8;
      w1p = Whb + (size_t)(1 * 1024 + nt * 16 + r) * HH + hk + kg * 8;
      w2p = Whb + (size_t)(2 * 1024 + nt * 16 + r) * HH + hk + kg * 8;
      w3p = Whb + (size_t)(3 * 1024 + nt * 16 + r) * HH + hk + kg * 8;
    }
    bf16x8 af  = *(const bf16x8*)a_h;
    bf16x8 alf = *(const bf16x8*)a_l;
    bf16x8 b0 = *(const bf16x8*)w0p;
    acc0 = __builtin_amdgcn_mfma_f32_16x16x32_bf16(af,  b0, acc0, 0, 0, 0);
    acc0 = __builtin_amdgcn_mfma_f32_16x16x32_bf16(alf, b0, acc0, 0, 0, 0);
    bf16x8 b1 = *(const bf16x8*)w1p;
    acc1 = __builtin_amdgcn_mfma_f32_16x16x32_bf16(af,  b1, acc1, 0, 0, 0);
    acc1 = __builtin_amdgcn_mfma_f32_16x16x32_bf16(alf, b1, acc1, 0, 0, 0);
    bf16x8 b2 = *(const bf16x8*)w2p;
    acc2 = __builtin_amdgcn_mfma_f32_16x16x32_bf16(af,  b2, acc2, 0, 0, 0);
    acc2 = __builtin_amdgcn_mfma_f32_16x16x32_bf16(alf, b2, acc2, 0, 0, 0);
    bf16x8 b3 = *(const bf16x8*)w3p;
    acc3 = __builtin_amdgcn_mfma_f32_16x16x32_bf16(af,  b3, acc3, 0, 0, 0);
    acc3 = __builtin_amdgcn_mfma_f32_16x16x32_bf16(alf, b3, acc3, 0, 0, 0);
  }

  if (w != 0) {
#pragma unroll
    for (int q = 0; q < 4; ++q) {
      red[w - 1][lane][0 * 4 + q] = acc0[q];
      red[w - 1][lane][1 * 4 + q] = acc1[q];
      red[w - 1][lane][2 * 4 + q] = acc2[q];
      red[w - 1][lane][3 * 4 + q] = acc3[q];
    }
  }
  __syncthreads();
  if (w == 0) {
    const int j = nt * 16 + r;
    const float b0 = bg[j], b1 = bg[1024 + j], b2 = bg[2048 + j], b3 = bg[3072 + j];
#pragma unroll
    for (int q = 0; q < 4; ++q) {
      const int bl = kg * 4 + q;
      float gi = acc0[q] + b0 + ctx_s[bl][0 * 16 + r];
      float gf = acc1[q] + b1 + ctx_s[bl][1 * 16 + r];
      float gg = acc2[q] + b2 + ctx_s[bl][2 * 16 + r];
      float go = acc3[q] + b3 + ctx_s[bl][3 * 16 + r];
#pragma unroll
      for (int p = 0; p < 3; ++p) {
        gi += red[p][lane][0 * 4 + q];
        gf += red[p][lane][1 * 4 + q];
        gg += red[p][lane][2 * 4 + q];
        go += red[p][lane][3 * 4 + q];
      }
      const int b = mq * 16 + bl;
      float si = 1.f / (1.f + expf(-gi));
      float sf = 1.f / (1.f + expf(-gf));
      float so = 1.f / (1.f + expf(-go));
      const size_t ci = (size_t)b * HH + j;
      float cc = sf * cbuf[ci] + si * tanhf(gg);
      float hh = so * tanhf(cc);
      cbuf[ci] = cc;
      short hi, lo; split2(hh, hi, lo);
      hHo[ci] = hi;
      hLo[ci] = lo;
    }
  }
}

// ---------------------------------------------------------------------------
// Generic LDS-tiled GEMM: out = A[M,K] @ W[N,K]^T. 128x128 tile, BK=32.
// OUTMODE: 0 = f32 row-major, 1 = bf16 row-major, 2 = bf16 ctx-remap
//   (col -> gate=col>>10, nt=(col>>4)&63, j=col&15;
//    out[(nt*3136 + row)*64 + gate*16 + j])
// ---------------------------------------------------------------------------
template<int OUTMODE>
__global__ __launch_bounds__(256) void tgemm_k(
    const short* __restrict__ A, const short* __restrict__ Wb,
    float* __restrict__ outf, short* __restrict__ outb,
    int M, int N, int K, int ldo)
{
  __shared__ short lA[128 * 40];
  __shared__ short lW[128 * 40];
  const int tid = threadIdx.x;
  const int w = tid >> 6, lane = tid & 63;
  const int r = lane & 15, kg = lane >> 4;
  const int m0 = blockIdx.x * 128;
  const int n0 = blockIdx.y * 128;
  const int srow = tid >> 2, scol = (tid & 3) * 8;

  f32x4 acc[2][8] = {};
  for (int k0 = 0; k0 < K; k0 += 32) {
    __syncthreads();
#pragma unroll
    for (int j = 0; j < 2; ++j) {
      const int row = j * 64 + srow;
      int ar = m0 + row; if (ar >= M) ar = M - 1;
      int wr = n0 + row; if (wr >= N) wr = N - 1;
      bf16x8 va = *(const bf16x8*)&A[(size_t)ar * K + k0 + scol];
      bf16x8 vw = *(const bf16x8*)&Wb[(size_t)wr * K + k0 + scol];
      *(bf16x8*)&lA[row * 40 + scol] = va;
      *(bf16x8*)&lW[row * 40 + scol] = vw;
    }
    __syncthreads();
    bf16x8 a0 = *(const bf16x8*)&lA[(w * 32 +  0 + r) * 40 + kg * 8];
    bf16x8 a1 = *(const bf16x8*)&lA[(w * 32 + 16 + r) * 40 + kg * 8];
#pragma unroll
    for (int nf = 0; nf < 8; ++nf) {
      bf16x8 wf = *(const bf16x8*)&lW[(nf * 16 + r) * 40 + kg * 8];
      acc[0][nf] = __builtin_amdgcn_mfma_f32_16x16x32_bf16(a0, wf, acc[0][nf], 0, 0, 0);
      acc[1][nf] = __builtin_amdgcn_mfma_f32_16x16x32_bf16(a1, wf, acc[1][nf], 0, 0, 0);
    }
  }
#pragma unroll
  for (int nf = 0; nf < 8; ++nf) {
    const int col = n0 + nf * 16 + r;
    if (col < N) {
#pragma unroll
      for (int mf = 0; mf < 2; ++mf)
#pragma unroll
        for (int q = 0; q < 4; ++q) {
          const int grow = m0 + w * 32 + mf * 16 + kg * 4 + q;
          if (grow < M) {
            if (OUTMODE == 0) {
              outf[(size_t)grow * ldo + col] = acc[mf][nf][q];
            } else if (OUTMODE == 1) {
              outb[(size_t)grow * ldo + col] = (short)bf16_rn(acc[mf][nf][q]);
            } else {
              const int gate = col >> 10, ntc = (col >> 4) & 63, jj = col & 15;
              outb[((size_t)ntc * 3136 + grow) * 64 + gate * 16 + jj] =
                  (short)bf16_rn(acc[mf][nf][q]);
            }
          }
        }
    }
  }
}

// ---------------------------------------------------------------------------
// Batched fc GEMM, LDS-staged 128x128 tile (round-10 proven). Grid (16, 94).
// ---------------------------------------------------------------------------
__global__ __launch_bounds__(256) void bgemm_k(
    const short* __restrict__ Ah, const short* __restrict__ Al,
    const short* __restrict__ Wb, const float* __restrict__ bias,
    float* __restrict__ outs)
{
  __shared__ short lAh[128 * 40];
  __shared__ short lAl[128 * 40];
  __shared__ short lW [128 * 40];
  const int tid = threadIdx.x;
  const int w = tid >> 6, lane = tid & 63;
  const int r = lane & 15, kg = lane >> 4;
  const int m0 = blockIdx.x * 128;
  const int n0 = blockIdx.y * 128;
  const int srow = tid >> 2, scol = (tid & 3) * 8;

  f32x4 acc[2][8] = {};
  for (int k0 = 0; k0 < HH; k0 += 32) {
    __syncthreads();
#pragma unroll
    for (int j = 0; j < 2; ++j) {
      const int row = j * 64 + srow;
      bf16x8 va = *(const bf16x8*)&Ah[(size_t)(m0 + row) * HH + k0 + scol];
      bf16x8 vl = *(const bf16x8*)&Al[(size_t)(m0 + row) * HH + k0 + scol];
      int wr = n0 + row; if (wr >= VV) wr = VV - 1;
      bf16x8 vw = *(const bf16x8*)&Wb[(size_t)wr * HH + k0 + scol];
      *(bf16x8*)&lAh[row * 40 + scol] = va;
      *(bf16x8*)&lAl[row * 40 + scol] = vl;
      *(bf16x8*)&lW [row * 40 + scol] = vw;
    }
    __syncthreads();
    bf16x8 ah0 = *(const bf16x8*)&lAh[(w * 32 +  0 + r) * 40 + kg * 8];
    bf16x8 ah1 = *(const bf16x8*)&lAh[(w * 32 + 16 + r) * 40 + kg * 8];
    bf16x8 al0 = *(const bf16x8*)&lAl[(w * 32 +  0 + r) * 40 + kg * 8];
    bf16x8 al1 = *(const bf16x8*)&lAl[(w * 32 + 16 + r) * 40 + kg * 8];
#pragma unroll
    for (int nf = 0; nf < 8; ++nf) {
      bf16x8 wf = *(const bf16x8*)&lW[(nf * 16 + r) * 40 + kg * 8];
      acc[0][nf] = __builtin_amdgcn_mfma_f32_16x16x32_bf16(ah0, wf, acc[0][nf], 0, 0, 0);
      acc[0][nf] = __builtin_amdgcn_mfma_f32_16x16x32_bf16(al0, wf, acc[0][nf], 0, 0, 0);
      acc[1][nf] = __builtin_amdgcn_mfma_f32_16x16x32_bf16(ah1, wf, acc[1][nf], 0, 0, 0);
      acc[1][nf] = __builtin_amdgcn_mfma_f32_16x16x32_bf16(al1, wf, acc[1][nf], 0, 0, 0);
    }
  }
#pragma unroll
  for (int nf = 0; nf < 8; ++nf) {
    const int colv = n0 + nf * 16 + r;
    if (colv < VV) {
      const float bv = bias[colv];
#pragma unroll
      for (int mf = 0; mf < 2; ++mf)
#pragma unroll
        for (int q = 0; q < 4; ++q) {
          const int grow = m0 + w * 32 + mf * 16 + kg * 4 + q;  // = t*64 + b
          const int tt = grow >> 6, b = grow & 63;
          outs[((size_t)b * TT + tt) * VV + colv] = acc[mf][nf][q] + bv;
        }
    }
  }
}

// ---------------------------------------------------------------------------
// MFMA GEMM used in one-time prep (h0, c0).
// ---------------------------------------------------------------------------
template<bool TWOPASS, bool SPLITOUT, int MT>
__global__ __launch_bounds__(256) void mgemm_k(
    const short* __restrict__ Ah, const short* __restrict__ Al, int lda,
    const short* __restrict__ Wb, int ldw,
    const float* __restrict__ bias,
    float* __restrict__ C, int ldc,
    short* __restrict__ Ch, short* __restrict__ Cl, int ldch,
    int N, int K)
{
  const int tid = threadIdx.x;
  const int w = tid >> 6, l = tid & 63;
  const int r = l & 15, kg = l >> 4;
  const int m0 = blockIdx.y * 64;
  const int nslice = (MT == 4) ? w : (w >> 1);
  const int mbase  = (MT == 4) ? 0 : ((w & 1) * 2);
  const int n0 = blockIdx.x * (MT * 16) + nslice * 16;
  const int nrow = n0 + r;
  const int nclmp = nrow < N ? nrow : N - 1;
  const short* wp  = Wb + (size_t)nclmp * ldw + kg * 8;
  const short* ap  = Ah + (size_t)(m0 + mbase * 16 + r) * lda + kg * 8;
  const short* alp = TWOPASS ? (Al + (size_t)(m0 + mbase * 16 + r) * lda + kg * 8)
                             : nullptr;
  f32x4 acc[MT] = {};
  for (int k0 = 0; k0 < K; k0 += 32) {
    bf16x8 bf = *(const bf16x8*)(wp + k0);
#pragma unroll
    for (int m = 0; m < MT; ++m) {
      bf16x8 af = *(const bf16x8*)(ap + (size_t)(16 * m) * lda + k0);
      acc[m] = __builtin_amdgcn_mfma_f32_16x16x32_bf16(af, bf, acc[m], 0, 0, 0);
      if (TWOPASS) {
        bf16x8 alf = *(const bf16x8*)(alp + (size_t)(16 * m) * lda + k0);
        acc[m] = __builtin_amdgcn_mfma_f32_16x16x32_bf16(alf, bf, acc[m], 0, 0, 0);
      }
    }
  }
  if (nrow < N) {
    float bv = bias ? bias[nrow] : 0.f;
#pragma unroll
    for (int m = 0; m < MT; ++m) {
#pragma unroll
      for (int q = 0; q < 4; ++q) {
        int mm = m0 + (mbase + m) * 16 + kg * 4 + q;
        float v = acc[m][q] + bv;
        if (SPLITOUT) {
          short hi, lo; split2(v, hi, lo);
          Ch[(size_t)mm * ldch + nrow] = hi;
          Cl[(size_t)mm * ldch + nrow] = lo;
        } else {
          C[(size_t)mm * ldc + nrow] = v;
        }
      }
    }
  }
}

__global__ __launch_bounds__(256) void transpose_split_k(
    const float* __restrict__ in, short* __restrict__ out, int R, int C)
{
  __shared__ float tile[32][33];
  int bc = blockIdx.x * 32, br = blockIdx.y * 32;
  int tx = threadIdx.x & 31, ty4 = (threadIdx.x >> 5) << 2;
#pragma unroll
  for (int i = 0; i < 4; ++i) {
    int r = br + ty4 + i, c = bc + tx;
    tile[ty4 + i][tx] = (r < R && c < C) ? in[(size_t)r * C + c] : 0.f;
  }
  __syncthreads();
#pragma unroll
  for (int i = 0; i < 4; ++i) {
    int oc = bc + ty4 + i, orr = br + tx;
    if (oc < C && orr < R) out[(size_t)oc * R + orr] = (short)bf16_rn(tile[tx][ty4 + i]);
  }
}

__global__ __launch_bounds__(256) void cast_k(
    const float* __restrict__ in, short* __restrict__ out, size_t n)
{
  for (size_t i = blockIdx.x * 256ULL + threadIdx.x; i < n; i += gridDim.x * 256ULL)
    out[i] = (short)bf16_rn(in[i]);
}

// Wxg[n][k] = bf16(W_ih[n][ k<512 ? k : EE+FF+(k-512) ])  (emb|cat cols)
__global__ __launch_bounds__(256) void wxg_k(const float* __restrict__ wih,
                                             short* __restrict__ out)
{
  for (size_t i = blockIdx.x * 256ULL + threadIdx.x; i < (size_t)4096 * XGLEN;
       i += gridDim.x * 256ULL) {
    const int n = i / XGLEN, k = i % XGLEN;
    const int ks = (k < EE) ? k : (EE + FF + (k - EE));
    out[i] = (short)bf16_rn(wih[(size_t)n * XKLEN + ks]);
  }
}

// Wctxb[n][k] = bf16(W_ih[n][EE + k]), k < 2048
__global__ __launch_bounds__(256) void wctx_k(const float* __restrict__ wih,
                                              short* __restrict__ out)
{
  for (size_t i = blockIdx.x * 256ULL + threadIdx.x; i < (size_t)4096 * FF;
       i += gridDim.x * 256ULL) {
    const int n = i / FF, k = i % FF;
    out[i] = (short)bf16_rn(wih[(size_t)n * XKLEN + EE + k]);
  }
}

// xg[t*64+b][0:512] = emb[cap[b][t]]; [512:640] = category[b]  (hi/lo split)
__global__ __launch_bounds__(256) void xg_k(
    const int* __restrict__ captions, const float* __restrict__ emb,
    const float* __restrict__ cat,
    short* __restrict__ xgH, short* __restrict__ xgL)
{
  for (size_t i = blockIdx.x * 256ULL + threadIdx.x; i < (size_t)2048 * XGLEN;
       i += gridDim.x * 256ULL) {
    const int row = i / XGLEN, k = i % XGLEN;
    const int t = row >> 6, b = row & 63;
    float v;
    if (k < EE) {
      const int cap = captions[b * TT + t];
      v = emb[(size_t)cap * EE + k];
    } else {
      v = cat[(size_t)b * CDIM + (k - EE)];
    }
    short hi, lo; split2(v, hi, lo);
    xgH[i] = hi;
    xgL[i] = lo;
  }
}

__global__ __launch_bounds__(256) void mean_k(
    const float* __restrict__ feat, short* __restrict__ mf)
{
  int idx = blockIdx.x * 256 + threadIdx.x;
  int b = idx >> 11, f = idx & 2047;
  float s = 0.f;
#pragma unroll
  for (int l = 0; l < LL; ++l) s += feat[((size_t)b * LL + l) * FF + f];
  mf[idx] = (short)bf16_rn(s * (1.f / 49.f));
}

__global__ __launch_bounds__(256) void setup_k(
    const float* __restrict__ b_ih, const float* __restrict__ b_hh,
    float* __restrict__ bg)
{
  int idx = blockIdx.x * 256 + threadIdx.x;
  if (idx < 4096) bg[idx] = b_ih[idx] + b_hh[idx];
}

extern "C" void kernel_launch(void* const* d_in, const int* in_sizes, int n_in,
                              void* d_out, int out_size, void* d_ws, size_t ws_size,
                              hipStream_t stream) {
  const int*   captions = (const int*)  d_in[0];
  const float* features = (const float*)d_in[1];
  const float* category = (const float*)d_in[2];
  const float* emb      = (const float*)d_in[3];
  const float* W_ih     = (const float*)d_in[4];
  const float* b_ih     = (const float*)d_in[5];
  const float* W_hh     = (const float*)d_in[6];
  const float* b_hh     = (const float*)d_in[7];
  const float* fc_W     = (const float*)d_in[8];
  const float* fc_b     = (const float*)d_in[9];
  const float* Wh0      = (const float*)d_in[10];
  const float* bh0      = (const float*)d_in[11];
  const float* Wc0      = (const float*)d_in[12];
  const float* bc0      = (const float*)d_in[13];
  const float* att_W    = (const float*)d_in[14];
  const float* att_U    = (const float*)d_in[15];
  const float* att_v    = (const float*)d_in[16];

  float* outs  = (float*)d_out;
  float* w_out = outs + (size_t)BB * TT * VV;

  char* p = (char*)d_ws;
  auto alloc = [&](size_t bytes) {
    char* q = p; p += (bytes + 255) & ~(size_t)255; return q;
  };
  short* attUt  = (short*)alloc((size_t)HH * HH * 2);
  short* attWt  = (short*)alloc((size_t)HH * FF * 2);
  short* featb  = (short*)alloc((size_t)BB * LL * FF * 2);   // prep only; reused as hall
  short* fcWb   = (short*)alloc((size_t)VV * HH * 2);
  short* Wctxb  = (short*)alloc((size_t)4096 * FF * 2);
  short* Whb    = (short*)alloc((size_t)4096 * HH * 2);
  short* Wxg    = (short*)alloc((size_t)4096 * XGLEN * 2);
  short* Wh0b   = (short*)alloc((size_t)HH * FF * 2);
  short* Wc0b   = (short*)alloc((size_t)HH * FF * 2);
  short* mfb    = (short*)alloc((size_t)BB * FF * 2);
  short* h0H    = (short*)alloc((size_t)BB * HH * 2);
  short* h0L    = (short*)alloc((size_t)BB * HH * 2);
  short* xgH    = (short*)alloc((size_t)2048 * XGLEN * 2);
  short* xgL    = (short*)alloc((size_t)2048 * XGLEN * 2);
  float* featp  = (float*)alloc((size_t)BB * LL * HH * 4);
  short* featCtx= (short*)alloc((size_t)64 * 3136 * 64 * 2);
  float* cbuf   = (float*)alloc((size_t)BB * HH * 4);
  float* partS  = (float*)alloc((size_t)64 * 3136 * 4);
  float* bg     = (float*)alloc(4096 * 4);
  // h history (= h(t) for t=0..31) aliases featb (dead after prep GEMMs).
  short* hallH = featb;
  short* hallL = featb + (size_t)TT * BB * HH;

  // ---- one-time prep ----
  transpose_split_k<<<dim3(32, 32), 256, 0, stream>>>(att_U, attUt, HH, HH);
  transpose_split_k<<<dim3(32, 64), 256, 0, stream>>>(att_W, attWt, FF, HH);
  cast_k<<<2048, 256, 0, stream>>>(features, featb, (size_t)BB * LL * FF);
  cast_k<<<2048, 256, 0, stream>>>(fc_W, fcWb, (size_t)VV * HH);
  cast_k<<<1024, 256, 0, stream>>>(Wh0, Wh0b, (size_t)HH * FF);
  cast_k<<<1024, 256, 0, stream>>>(Wc0, Wc0b, (size_t)HH * FF);
  cast_k<<<1024, 256, 0, stream>>>(W_hh, Whb, (size_t)4096 * HH);
  wxg_k<<<2048, 256, 0, stream>>>(W_ih, Wxg);
  wctx_k<<<4096, 256, 0, stream>>>(W_ih, Wctxb);
  xg_k<<<2048, 256, 0, stream>>>(captions, emb, category, xgH, xgL);
  setup_k<<<16, 256, 0, stream>>>(b_ih, b_hh, bg);
  mean_k<<<512, 256, 0, stream>>>(features, mfb);

  // h0 / c0
  mgemm_k<false, true, 2><<<dim3(32, 1), 256, 0, stream>>>(
      mfb, nullptr, FF, Wh0b, FF, bh0,
      nullptr, 0, h0H, h0L, HH, HH, FF);
  mgemm_k<false, false, 2><<<dim3(32, 1), 256, 0, stream>>>(
      mfb, nullptr, FF, Wc0b, FF, bc0,
      cbuf, HH, nullptr, nullptr, 0, HH, FF);
  // featp = features @ att_W   (fp32 out, [3136][1024])
  tgemm_k<0><<<dim3(25, 8), 256, 0, stream>>>(
      featb, attWt, featp, nullptr, BB * LL, HH, FF, HH);
  // featCtx = features @ W_ih_ctx^T  (bf16, remapped to [64 nt][3136][64])
  tgemm_k<2><<<dim3(25, 32), 256, 0, stream>>>(
      featb, Wctxb, nullptr, featCtx, BB * LL, 4096, FF, 0);

  // ---- timestep loop: 2 dispatches per step ----
  for (int t = 0; t < TT; ++t) {
    const short* hHi = (t == 0) ? h0H : hallH + (size_t)(t - 1) * BB * HH;
    const short* hLi = (t == 0) ? h0L : hallL + (size_t)(t - 1) * BB * HH;
    hupart_k<<<dim3(64, 2), 256, 0, stream>>>(
        hHi, hLi, attUt, featp, att_v, partS);
    glstm3_k<<<dim3(64, 4), 256, 0, stream>>>(
        xgH, xgL, hHi, hLi, Wxg, Whb, featCtx, partS, bg, cbuf,
        hallH + (size_t)t * BB * HH, hallL + (size_t)t * BB * HH, w_out, t);
  }

  // ---- deferred batched fc ----
  bgemm_k<<<dim3(16, 94), 256, 0, stream>>>(hallH, hallL, fcWb, fc_b, outs);
}

// Round 15
// 2105.973 us; speedup vs baseline: 23.2349x; 1.1923x over previous
//
#include <hip/hip_runtime.h>
#include <hip/hip_bf16.h>

#define BB 64
#define TT 32
#define VV 12000
#define EE 512
#define FF 2048
#define CDIM 128
#define HH 1024
#define LL 49
#define XKLEN 2688   /* E + F + C */
#define XGLEN 640    /* E + C : per-step gathered input */

typedef __attribute__((ext_vector_type(8))) short bf16x8;
typedef __attribute__((ext_vector_type(4))) float f32x4;

__device__ __forceinline__ unsigned short bf16_rn(float x) {
  unsigned u = __float_as_uint(x);
  u += 0x7FFFu + ((u >> 16) & 1u);
  return (unsigned short)(u >> 16);
}
__device__ __forceinline__ float bf16_tof(unsigned short h) {
  return __uint_as_float(((unsigned)h) << 16);
}
__device__ __forceinline__ void split2(float x, short& hi, short& lo) {
  unsigned short h = bf16_rn(x);
  float r = x - bf16_tof(h);
  hi = (short)h;
  lo = (short)bf16_rn(r);
}

// ---------------------------------------------------------------------------
// D1: hU tile + partial scores. Grid 256 (XCD-swizzled: id=(bid&7)*32+bid>>3,
// nt=id>>2, mh=id&3 -> each XCD owns 8 nt-slices). 16 b-rows per block.
// partS layout: [64 nt][64 b][49 l]
// ---------------------------------------------------------------------------
__global__ __launch_bounds__(256) void hupart_k(
    const short* __restrict__ hHi, const short* __restrict__ hLi,
    const short* __restrict__ attUt,   // [1024][1024] bf16 = att_U^T
    const float* __restrict__ featp,   // [B*L][1024] f32
    const float* __restrict__ att_v,
    float* __restrict__ partS)         // [64 nt][64 b][49 l]
{
  __shared__ float red[4][64][5];
  __shared__ float hu_s[16][17];
  __shared__ float av_s[16];
  const int tid = threadIdx.x;
  const int w = tid >> 6, lane = tid & 63;
  const int r = lane & 15, kg = lane >> 4;
  const int bid = blockIdx.x;
  const int id = (bid & 7) * 32 + (bid >> 3);
  const int nt = id >> 2, mh = id & 3;
  const int kb = w * 256;

  if (tid < 16) av_s[tid] = att_v[nt * 16 + tid];

  const short* wp  = attUt + (size_t)(nt * 16 + r) * HH + kb + kg * 8;
  const short* ap  = hHi + (size_t)(mh * 16 + r) * HH + kb + kg * 8;
  const short* alp = hLi + (size_t)(mh * 16 + r) * HH + kb + kg * 8;
  f32x4 acc = {};
#pragma unroll
  for (int k0 = 0; k0 < 256; k0 += 32) {
    bf16x8 bf = *(const bf16x8*)(wp + k0);
    bf16x8 af = *(const bf16x8*)(ap + k0);
    acc = __builtin_amdgcn_mfma_f32_16x16x32_bf16(af, bf, acc, 0, 0, 0);
    bf16x8 alf = *(const bf16x8*)(alp + k0);
    acc = __builtin_amdgcn_mfma_f32_16x16x32_bf16(alf, bf, acc, 0, 0, 0);
  }
#pragma unroll
  for (int q = 0; q < 4; ++q)
    red[w][lane][q] = acc[q];
  __syncthreads();

  // assemble hU[16 b][16 a] from the 4 K-quarters
  {
    const int bl = tid >> 4, a = tid & 15;       // 256 tasks exactly
    const int sl = (bl >> 2) * 16 + a;           // source lane
    const int ii = bl & 3;                       // reg index
    hu_s[bl][a] = red[0][sl][ii] + red[1][sl][ii] + red[2][sl][ii] + red[3][sl][ii];
  }
  __syncthreads();

  // partial scores for this a-slice: 16 b x 49 l = 784 tasks
  for (int task = tid; task < 16 * LL; task += 256) {
    const int bl = task / LL, l = task - bl * LL;
    const int b = mh * 16 + bl;
    const float* fp = featp + ((size_t)b * LL + l) * HH + nt * 16;
    float s = 0.f;
#pragma unroll
    for (int a = 0; a < 16; ++a)
      s += tanhf(fp[a] + hu_s[bl][a]) * av_s[a];
    // [nt][b][l] with b*49+l = mh*784 + task -> contiguous in task
    partS[(size_t)nt * 3136 + (size_t)mh * 784 + task] = s;
  }
}

// ---------------------------------------------------------------------------
// D2: softmax + ctx-weighted-sum + gates MFMA ([xg|h] segments) + LSTM.
// Grid 256 (XCD-swizzled like D1: nt=id>>2, mq=id&3). h out to hall[t].
// featCtx layout: [nt][3136][64]
// ---------------------------------------------------------------------------
__global__ __launch_bounds__(256) void glstm3_k(
    const short* __restrict__ xgH, const short* __restrict__ xgL,  // [2048][640]
    const short* __restrict__ hHi, const short* __restrict__ hLi,  // [64][1024] = h(t-1)
    const short* __restrict__ Wxg,      // [4096][640]
    const short* __restrict__ Whb,      // [4096][1024]
    const short* __restrict__ featCtx,  // [64][3136][64] bf16
    const float* __restrict__ partS,    // [64 nt][64 b][49 l]
    const float* __restrict__ bg,
    float* __restrict__ cbuf,
    short* __restrict__ hHo, short* __restrict__ hLo,  // h(t) out (hall slot t)
    float* __restrict__ w_out, int t)
{
  __shared__ float sw[16][52];
  __shared__ float ctx_s[16][68];
  __shared__ float red[3][64][17];
  const int tid = threadIdx.x;
  const int w = tid >> 6, lane = tid & 63;
  const int r = lane & 15, kg = lane >> 4;
  const int bid = blockIdx.x;
  const int id = (bid & 7) * 32 + (bid >> 3);
  const int nt = id >> 2, mq = id & 3;

  // Phase A: raw scores for this block's 16 b's (coalesced nt-major reads)
  for (int idx = tid; idx < 16 * LL; idx += 256) {
    const float* ps = partS + (size_t)mq * 784 + idx;
    float s = 0.f;
#pragma unroll 8
    for (int a = 0; a < 64; ++a) s += ps[(size_t)a * 3136];
    sw[idx / LL][idx % LL] = s;
  }
  __syncthreads();
  // softmax: wave w handles b_loc = w*4 .. +3
#pragma unroll
  for (int i = 0; i < 4; ++i) {
    const int bl = w * 4 + i;
    float v = (lane < LL) ? sw[bl][lane] : -1e30f;
    float m = v;
#pragma unroll
    for (int off = 32; off > 0; off >>= 1) m = fmaxf(m, __shfl_xor(m, off));
    float e = (lane < LL) ? expf(v - m) : 0.f;
    float s = e;
#pragma unroll
    for (int off = 32; off > 0; off >>= 1) s += __shfl_xor(s, off);
    float ww = e / s;
    if (lane < LL) {
      sw[bl][lane] = ww;
      if (nt == 0)
        w_out[((size_t)(mq * 16 + bl) * TT + t) * LL + lane] = ww;
    }
  }
  __syncthreads();

  // Phase B: ctx_s[bl][e] = sum_l w[bl][l] * featCtx[nt][(b*49+l)][e], e=gate*16+j
  {
    const int bl = tid >> 4, e4 = (tid & 15) * 4;
    const size_t base =
        ((size_t)nt * 3136 + (size_t)(mq * 16 + bl) * LL) * 64 + e4;
    float s0 = 0.f, s1 = 0.f, s2 = 0.f, s3 = 0.f;
#pragma unroll
    for (int l = 0; l < LL; ++l) {
      short4 v = *(const short4*)&featCtx[base + (size_t)l * 64];
      const float wl = sw[bl][l];
      s0 += wl * bf16_tof((unsigned short)v.x);
      s1 += wl * bf16_tof((unsigned short)v.y);
      s2 += wl * bf16_tof((unsigned short)v.z);
      s3 += wl * bf16_tof((unsigned short)v.w);
    }
    ctx_s[bl][e4 + 0] = s0;
    ctx_s[bl][e4 + 1] = s1;
    ctx_s[bl][e4 + 2] = s2;
    ctx_s[bl][e4 + 3] = s3;
  }

  // Phase C: gates MFMA over [xg(640) | h(1024)], K split 4 waves x 13 chunks
  const int brow = mq * 16 + r;
  const size_t xgrow = (size_t)t * 64 + brow;
  f32x4 acc0 = {}, acc1 = {}, acc2 = {}, acc3 = {};
#pragma unroll
  for (int c = 0; c < 13; ++c) {
    const int gk = (w * 13 + c) * 32;
    const short *a_h, *a_l, *w0p, *w1p, *w2p, *w3p;
    if (gk < XGLEN) {
      a_h = xgH + xgrow * XGLEN + gk + kg * 8;
      a_l = xgL + xgrow * XGLEN + gk + kg * 8;
      w0p = Wxg + (size_t)(0 * 1024 + nt * 16 + r) * XGLEN + gk + kg * 8;
      w1p = Wxg + (size_t)(1 * 1024 + nt * 16 + r) * XGLEN + gk + kg * 8;
      w2p = Wxg + (size_t)(2 * 1024 + nt * 16 + r) * XGLEN + gk + kg * 8;
      w3p = Wxg + (size_t)(3 * 1024 + nt * 16 + r) * XGLEN + gk + kg * 8;
    } else {
      const int hk = gk - XGLEN;
      a_h = hHi + (size_t)brow * HH + hk + kg * 8;
      a_l = hLi + (size_t)brow * HH + hk + kg * 8;
      w0p = Whb + (size_t)(0 * 1024 + nt * 16 + r) * HH + hk + kg * 8;
      w1p = Whb + (size_t)(1 * 1024 + nt * 16 + r) * HH + hk + kg * 8;
      w2p = Whb + (size_t)(2 * 1024 + nt * 16 + r) * HH + hk + kg * 8;
      w3p = Whb + (size_t)(3 * 1024 + nt * 16 + r) * HH + hk + kg * 8;
    }
    bf16x8 af  = *(const bf16x8*)a_h;
    bf16x8 alf = *(const bf16x8*)a_l;
    bf16x8 b0 = *(const bf16x8*)w0p;
    acc0 = __builtin_amdgcn_mfma_f32_16x16x32_bf16(af,  b0, acc0, 0, 0, 0);
    acc0 = __builtin_amdgcn_mfma_f32_16x16x32_bf16(alf, b0, acc0, 0, 0, 0);
    bf16x8 b1 = *(const bf16x8*)w1p;
    acc1 = __builtin_amdgcn_mfma_f32_16x16x32_bf16(af,  b1, acc1, 0, 0, 0);
    acc1 = __builtin_amdgcn_mfma_f32_16x16x32_bf16(alf, b1, acc1, 0, 0, 0);
    bf16x8 b2 = *(const bf16x8*)w2p;
    acc2 = __builtin_amdgcn_mfma_f32_16x16x32_bf16(af,  b2, acc2, 0, 0, 0);
    acc2 = __builtin_amdgcn_mfma_f32_16x16x32_bf16(alf, b2, acc2, 0, 0, 0);
    bf16x8 b3 = *(const bf16x8*)w3p;
    acc3 = __builtin_amdgcn_mfma_f32_16x16x32_bf16(af,  b3, acc3, 0, 0, 0);
    acc3 = __builtin_amdgcn_mfma_f32_16x16x32_bf16(alf, b3, acc3, 0, 0, 0);
  }

  if (w != 0) {
#pragma unroll
    for (int q = 0; q < 4; ++q) {
      red[w - 1][lane][0 * 4 + q] = acc0[q];
      red[w - 1][lane][1 * 4 + q] = acc1[q];
      red[w - 1][lane][2 * 4 + q] = acc2[q];
      red[w - 1][lane][3 * 4 + q] = acc3[q];
    }
  }
  __syncthreads();
  if (w == 0) {
    const int j = nt * 16 + r;
    const float b0 = bg[j], b1 = bg[1024 + j], b2 = bg[2048 + j], b3 = bg[3072 + j];
#pragma unroll
    for (int q = 0; q < 4; ++q) {
      const int bl = kg * 4 + q;
      float gi = acc0[q] + b0 + ctx_s[bl][0 * 16 + r];
      float gf = acc1[q] + b1 + ctx_s[bl][1 * 16 + r];
      float gg = acc2[q] + b2 + ctx_s[bl][2 * 16 + r];
      float go = acc3[q] + b3 + ctx_s[bl][3 * 16 + r];
#pragma unroll
      for (int p = 0; p < 3; ++p) {
        gi += red[p][lane][0 * 4 + q];
        gf += red[p][lane][1 * 4 + q];
        gg += red[p][lane][2 * 4 + q];
        go += red[p][lane][3 * 4 + q];
      }
      const int b = mq * 16 + bl;
      float si = 1.f / (1.f + expf(-gi));
      float sf = 1.f / (1.f + expf(-gf));
      float so = 1.f / (1.f + expf(-go));
      const size_t ci = (size_t)b * HH + j;
      float cc = sf * cbuf[ci] + si * tanhf(gg);
      float hh = so * tanhf(cc);
      cbuf[ci] = cc;
      short hi, lo; split2(hh, hi, lo);
      hHo[ci] = hi;
      hLo[ci] = lo;
    }
  }
}

// ---------------------------------------------------------------------------
// Generic LDS-tiled GEMM: out = A[M,K] @ W[N,K]^T. 128x128 tile, BK=32.
// OUTMODE: 0 = f32 row-major, 2 = bf16 ctx-remap
// ---------------------------------------------------------------------------
template<int OUTMODE>
__global__ __launch_bounds__(256) void tgemm_k(
    const short* __restrict__ A, const short* __restrict__ Wb,
    float* __restrict__ outf, short* __restrict__ outb,
    int M, int N, int K, int ldo)
{
  __shared__ short lA[128 * 40];
  __shared__ short lW[128 * 40];
  const int tid = threadIdx.x;
  const int w = tid >> 6, lane = tid & 63;
  const int r = lane & 15, kg = lane >> 4;
  const int m0 = blockIdx.x * 128;
  const int n0 = blockIdx.y * 128;
  const int srow = tid >> 2, scol = (tid & 3) * 8;

  f32x4 acc[2][8] = {};
  for (int k0 = 0; k0 < K; k0 += 32) {
    __syncthreads();
#pragma unroll
    for (int j = 0; j < 2; ++j) {
      const int row = j * 64 + srow;
      int ar = m0 + row; if (ar >= M) ar = M - 1;
      int wr = n0 + row; if (wr >= N) wr = N - 1;
      bf16x8 va = *(const bf16x8*)&A[(size_t)ar * K + k0 + scol];
      bf16x8 vw = *(const bf16x8*)&Wb[(size_t)wr * K + k0 + scol];
      *(bf16x8*)&lA[row * 40 + scol] = va;
      *(bf16x8*)&lW[row * 40 + scol] = vw;
    }
    __syncthreads();
    bf16x8 a0 = *(const bf16x8*)&lA[(w * 32 +  0 + r) * 40 + kg * 8];
    bf16x8 a1 = *(const bf16x8*)&lA[(w * 32 + 16 + r) * 40 + kg * 8];
#pragma unroll
    for (int nf = 0; nf < 8; ++nf) {
      bf16x8 wf = *(const bf16x8*)&lW[(nf * 16 + r) * 40 + kg * 8];
      acc[0][nf] = __builtin_amdgcn_mfma_f32_16x16x32_bf16(a0, wf, acc[0][nf], 0, 0, 0);
      acc[1][nf] = __builtin_amdgcn_mfma_f32_16x16x32_bf16(a1, wf, acc[1][nf], 0, 0, 0);
    }
  }
#pragma unroll
  for (int nf = 0; nf < 8; ++nf) {
    const int col = n0 + nf * 16 + r;
    if (col < N) {
#pragma unroll
      for (int mf = 0; mf < 2; ++mf)
#pragma unroll
        for (int q = 0; q < 4; ++q) {
          const int grow = m0 + w * 32 + mf * 16 + kg * 4 + q;
          if (grow < M) {
            if (OUTMODE == 0) {
              outf[(size_t)grow * ldo + col] = acc[mf][nf][q];
            } else {
              const int gate = col >> 10, ntc = (col >> 4) & 63, jj = col & 15;
              outb[((size_t)ntc * 3136 + grow) * 64 + gate * 16 + jj] =
                  (short)bf16_rn(acc[mf][nf][q]);
            }
          }
        }
    }
  }
}

// ---------------------------------------------------------------------------
// Batched fc GEMM, LDS-staged 128x128 tile. Grid (16, 94).
// ---------------------------------------------------------------------------
__global__ __launch_bounds__(256) void bgemm_k(
    const short* __restrict__ Ah, const short* __restrict__ Al,
    const short* __restrict__ Wb, const float* __restrict__ bias,
    float* __restrict__ outs)
{
  __shared__ short lAh[128 * 40];
  __shared__ short lAl[128 * 40];
  __shared__ short lW [128 * 40];
  const int tid = threadIdx.x;
  const int w = tid >> 6, lane = tid & 63;
  const int r = lane & 15, kg = lane >> 4;
  const int m0 = blockIdx.x * 128;
  const int n0 = blockIdx.y * 128;
  const int srow = tid >> 2, scol = (tid & 3) * 8;

  f32x4 acc[2][8] = {};
  for (int k0 = 0; k0 < HH; k0 += 32) {
    __syncthreads();
#pragma unroll
    for (int j = 0; j < 2; ++j) {
      const int row = j * 64 + srow;
      bf16x8 va = *(const bf16x8*)&Ah[(size_t)(m0 + row) * HH + k0 + scol];
      bf16x8 vl = *(const bf16x8*)&Al[(size_t)(m0 + row) * HH + k0 + scol];
      int wr = n0 + row; if (wr >= VV) wr = VV - 1;
      bf16x8 vw = *(const bf16x8*)&Wb[(size_t)wr * HH + k0 + scol];
      *(bf16x8*)&lAh[row * 40 + scol] = va;
      *(bf16x8*)&lAl[row * 40 + scol] = vl;
      *(bf16x8*)&lW [row * 40 + scol] = vw;
    }
    __syncthreads();
    bf16x8 ah0 = *(const bf16x8*)&lAh[(w * 32 +  0 + r) * 40 + kg * 8];
    bf16x8 ah1 = *(const bf16x8*)&lAh[(w * 32 + 16 + r) * 40 + kg * 8];
    bf16x8 al0 = *(const bf16x8*)&lAl[(w * 32 +  0 + r) * 40 + kg * 8];
    bf16x8 al1 = *(const bf16x8*)&lAl[(w * 32 + 16 + r) * 40 + kg * 8];
#pragma unroll
    for (int nf = 0; nf < 8; ++nf) {
      bf16x8 wf = *(const bf16x8*)&lW[(nf * 16 + r) * 40 + kg * 8];
      acc[0][nf] = __builtin_amdgcn_mfma_f32_16x16x32_bf16(ah0, wf, acc[0][nf], 0, 0, 0);
      acc[0][nf] = __builtin_amdgcn_mfma_f32_16x16x32_bf16(al0, wf, acc[0][nf], 0, 0, 0);
      acc[1][nf] = __builtin_amdgcn_mfma_f32_16x16x32_bf16(ah1, wf, acc[1][nf], 0, 0, 0);
      acc[1][nf] = __builtin_amdgcn_mfma_f32_16x16x32_bf16(al1, wf, acc[1][nf], 0, 0, 0);
    }
  }
#pragma unroll
  for (int nf = 0; nf < 8; ++nf) {
    const int colv = n0 + nf * 16 + r;
    if (colv < VV) {
      const float bv = bias[colv];
#pragma unroll
      for (int mf = 0; mf < 2; ++mf)
#pragma unroll
        for (int q = 0; q < 4; ++q) {
          const int grow = m0 + w * 32 + mf * 16 + kg * 4 + q;  // = t*64 + b
          const int tt = grow >> 6, b = grow & 63;
          outs[((size_t)b * TT + tt) * VV + colv] = acc[mf][nf][q] + bv;
        }
    }
  }
}

// ---------------------------------------------------------------------------
// MFMA GEMM used in one-time prep (h0, c0).
// ---------------------------------------------------------------------------
template<bool TWOPASS, bool SPLITOUT, int MT>
__global__ __launch_bounds__(256) void mgemm_k(
    const short* __restrict__ Ah, const short* __restrict__ Al, int lda,
    const short* __restrict__ Wb, int ldw,
    const float* __restrict__ bias,
    float* __restrict__ C, int ldc,
    short* __restrict__ Ch, short* __restrict__ Cl, int ldch,
    int N, int K)
{
  const int tid = threadIdx.x;
  const int w = tid >> 6, l = tid & 63;
  const int r = l & 15, kg = l >> 4;
  const int m0 = blockIdx.y * 64;
  const int nslice = (MT == 4) ? w : (w >> 1);
  const int mbase  = (MT == 4) ? 0 : ((w & 1) * 2);
  const int n0 = blockIdx.x * (MT * 16) + nslice * 16;
  const int nrow = n0 + r;
  const int nclmp = nrow < N ? nrow : N - 1;
  const short* wp  = Wb + (size_t)nclmp * ldw + kg * 8;
  const short* ap  = Ah + (size_t)(m0 + mbase * 16 + r) * lda + kg * 8;
  const short* alp = TWOPASS ? (Al + (size_t)(m0 + mbase * 16 + r) * lda + kg * 8)
                             : nullptr;
  f32x4 acc[MT] = {};
  for (int k0 = 0; k0 < K; k0 += 32) {
    bf16x8 bf = *(const bf16x8*)(wp + k0);
#pragma unroll
    for (int m = 0; m < MT; ++m) {
      bf16x8 af = *(const bf16x8*)(ap + (size_t)(16 * m) * lda + k0);
      acc[m] = __builtin_amdgcn_mfma_f32_16x16x32_bf16(af, bf, acc[m], 0, 0, 0);
      if (TWOPASS) {
        bf16x8 alf = *(const bf16x8*)(alp + (size_t)(16 * m) * lda + k0);
        acc[m] = __builtin_amdgcn_mfma_f32_16x16x32_bf16(alf, bf, acc[m], 0, 0, 0);
      }
    }
  }
  if (nrow < N) {
    float bv = bias ? bias[nrow] : 0.f;
#pragma unroll
    for (int m = 0; m < MT; ++m) {
#pragma unroll
      for (int q = 0; q < 4; ++q) {
        int mm = m0 + (mbase + m) * 16 + kg * 4 + q;
        float v = acc[m][q] + bv;
        if (SPLITOUT) {
          short hi, lo; split2(v, hi, lo);
          Ch[(size_t)mm * ldch + nrow] = hi;
          Cl[(size_t)mm * ldch + nrow] = lo;
        } else {
          C[(size_t)mm * ldc + nrow] = v;
        }
      }
    }
  }
}

__global__ __launch_bounds__(256) void transpose_split_k(
    const float* __restrict__ in, short* __restrict__ out, int R, int C)
{
  __shared__ float tile[32][33];
  int bc = blockIdx.x * 32, br = blockIdx.y * 32;
  int tx = threadIdx.x & 31, ty4 = (threadIdx.x >> 5) << 2;
#pragma unroll
  for (int i = 0; i < 4; ++i) {
    int r = br + ty4 + i, c = bc + tx;
    tile[ty4 + i][tx] = (r < R && c < C) ? in[(size_t)r * C + c] : 0.f;
  }
  __syncthreads();
#pragma unroll
  for (int i = 0; i < 4; ++i) {
    int oc = bc + ty4 + i, orr = br + tx;
    if (oc < C && orr < R) out[(size_t)oc * R + orr] = (short)bf16_rn(tile[tx][ty4 + i]);
  }
}

// ---------------------------------------------------------------------------
// Fused elementwise prep: all casts / weight-slicing / xg gather / bg / mean.
// Grid-stride over segment table. Grid 2048 x 256.
// ---------------------------------------------------------------------------
#define S_FEATB   6422528ULL                       /* 64*49*2048      */
#define C1  (S_FEATB)
#define C2  (C1 + 12288000ULL)                     /* fc_W 12000*1024 */
#define C3  (C2 + 4194304ULL)                      /* W_hh 4096*1024  */
#define C4  (C3 + 2097152ULL)                      /* Wh0 1024*2048   */
#define C5  (C4 + 2097152ULL)                      /* Wc0 1024*2048   */
#define C6  (C5 + 2621440ULL)                      /* Wxg 4096*640    */
#define C7  (C6 + 8388608ULL)                      /* Wctx 4096*2048  */
#define C8  (C7 + 1310720ULL)                      /* xg 2048*640     */
#define C9  (C8 + 4096ULL)                         /* bg              */
#define C10 (C9 + 131072ULL)                       /* mean 64*2048    */

__global__ __launch_bounds__(256) void prep_k(
    const float* __restrict__ features, const float* __restrict__ fc_W,
    const float* __restrict__ W_hh, const float* __restrict__ Wh0,
    const float* __restrict__ Wc0, const float* __restrict__ W_ih,
    const int* __restrict__ captions, const float* __restrict__ emb,
    const float* __restrict__ cat,
    const float* __restrict__ b_ih, const float* __restrict__ b_hh,
    short* __restrict__ featb, short* __restrict__ fcWb,
    short* __restrict__ Whb, short* __restrict__ Wh0b,
    short* __restrict__ Wc0b, short* __restrict__ Wxg,
    short* __restrict__ Wctxb, short* __restrict__ xgH,
    short* __restrict__ xgL, float* __restrict__ bg,
    short* __restrict__ mfb)
{
  const size_t stride = (size_t)gridDim.x * 256;
  for (size_t i = (size_t)blockIdx.x * 256 + threadIdx.x; i < C10; i += stride) {
    if (i < C1) {
      featb[i] = (short)bf16_rn(features[i]);
    } else if (i < C2) {
      size_t j = i - C1;
      fcWb[j] = (short)bf16_rn(fc_W[j]);
    } else if (i < C3) {
      size_t j = i - C2;
      Whb[j] = (short)bf16_rn(W_hh[j]);
    } else if (i < C4) {
      size_t j = i - C3;
      Wh0b[j] = (short)bf16_rn(Wh0[j]);
    } else if (i < C5) {
      size_t j = i - C4;
      Wc0b[j] = (short)bf16_rn(Wc0[j]);
    } else if (i < C6) {
      size_t j = i - C5;
      int n = j / XGLEN, k = j % XGLEN;
      int ks = (k < EE) ? k : (EE + FF + (k - EE));
      Wxg[j] = (short)bf16_rn(W_ih[(size_t)n * XKLEN + ks]);
    } else if (i < C7) {
      size_t j = i - C6;
      int n = j / FF, k = j % FF;
      Wctxb[j] = (short)bf16_rn(W_ih[(size_t)n * XKLEN + EE + k]);
    } else if (i < C8) {
      size_t j = i - C7;
      int row = j / XGLEN, k = j % XGLEN;
      int t = row >> 6, b = row & 63;
      float v;
      if (k < EE) {
        int cap = captions[b * TT + t];
        v = emb[(size_t)cap * EE + k];
      } else {
        v = cat[(size_t)b * CDIM + (k - EE)];
      }
      short hi, lo; split2(v, hi, lo);
      xgH[j] = hi;
      xgL[j] = lo;
    } else if (i < C9) {
      size_t j = i - C8;
      bg[j] = b_ih[j] + b_hh[j];
    } else {
      size_t j = i - C9;
      int b = j >> 11, f = j & 2047;
      float s = 0.f;
#pragma unroll
      for (int l = 0; l < LL; ++l) s += features[((size_t)b * LL + l) * FF + f];
      mfb[j] = (short)bf16_rn(s * (1.f / 49.f));
    }
  }
}

extern "C" void kernel_launch(void* const* d_in, const int* in_sizes, int n_in,
                              void* d_out, int out_size, void* d_ws, size_t ws_size,
                              hipStream_t stream) {
  const int*   captions = (const int*)  d_in[0];
  const float* features = (const float*)d_in[1];
  const float* category = (const float*)d_in[2];
  const float* emb      = (const float*)d_in[3];
  const float* W_ih     = (const float*)d_in[4];
  const float* b_ih     = (const float*)d_in[5];
  const float* W_hh     = (const float*)d_in[6];
  const float* b_hh     = (const float*)d_in[7];
  const float* fc_W     = (const float*)d_in[8];
  const float* fc_b     = (const float*)d_in[9];
  const float* Wh0      = (const float*)d_in[10];
  const float* bh0      = (const float*)d_in[11];
  const float* Wc0      = (const float*)d_in[12];
  const float* bc0      = (const float*)d_in[13];
  const float* att_W    = (const float*)d_in[14];
  const float* att_U    = (const float*)d_in[15];
  const float* att_v    = (const float*)d_in[16];

  float* outs  = (float*)d_out;
  float* w_out = outs + (size_t)BB * TT * VV;

  char* p = (char*)d_ws;
  auto alloc = [&](size_t bytes) {
    char* q = p; p += (bytes + 255) & ~(size_t)255; return q;
  };
  short* attUt  = (short*)alloc((size_t)HH * HH * 2);
  short* attWt  = (short*)alloc((size_t)HH * FF * 2);
  short* featb  = (short*)alloc((size_t)BB * LL * FF * 2);   // prep only; reused as hall
  short* fcWb   = (short*)alloc((size_t)VV * HH * 2);
  short* Wctxb  = (short*)alloc((size_t)4096 * FF * 2);
  short* Whb    = (short*)alloc((size_t)4096 * HH * 2);
  short* Wxg    = (short*)alloc((size_t)4096 * XGLEN * 2);
  short* Wh0b   = (short*)alloc((size_t)HH * FF * 2);
  short* Wc0b   = (short*)alloc((size_t)HH * FF * 2);
  short* mfb    = (short*)alloc((size_t)BB * FF * 2);
  short* h0H    = (short*)alloc((size_t)BB * HH * 2);
  short* h0L    = (short*)alloc((size_t)BB * HH * 2);
  short* xgH    = (short*)alloc((size_t)2048 * XGLEN * 2);
  short* xgL    = (short*)alloc((size_t)2048 * XGLEN * 2);
  float* featp  = (float*)alloc((size_t)BB * LL * HH * 4);
  short* featCtx= (short*)alloc((size_t)64 * 3136 * 64 * 2);
  float* cbuf   = (float*)alloc((size_t)BB * HH * 4);
  float* partS  = (float*)alloc((size_t)64 * 3136 * 4);
  float* bg     = (float*)alloc(4096 * 4);
  // h history (= h(t) for t=0..31) aliases featb (dead after prep GEMMs).
  short* hallH = featb;
  short* hallL = featb + (size_t)TT * BB * HH;

  // ---- one-time prep ----
  prep_k<<<2048, 256, 0, stream>>>(
      features, fc_W, W_hh, Wh0, Wc0, W_ih, captions, emb, category,
      b_ih, b_hh,
      featb, fcWb, Whb, Wh0b, Wc0b, Wxg, Wctxb, xgH, xgL, bg, mfb);
  transpose_split_k<<<dim3(32, 32), 256, 0, stream>>>(att_U, attUt, HH, HH);
  transpose_split_k<<<dim3(32, 64), 256, 0, stream>>>(att_W, attWt, FF, HH);

  // h0 / c0
  mgemm_k<false, true, 2><<<dim3(32, 1), 256, 0, stream>>>(
      mfb, nullptr, FF, Wh0b, FF, bh0,
      nullptr, 0, h0H, h0L, HH, HH, FF);
  mgemm_k<false, false, 2><<<dim3(32, 1), 256, 0, stream>>>(
      mfb, nullptr, FF, Wc0b, FF, bc0,
      cbuf, HH, nullptr, nullptr, 0, HH, FF);
  // featp = features @ att_W   (fp32 out, [3136][1024])
  tgemm_k<0><<<dim3(25, 8), 256, 0, stream>>>(
      featb, attWt, featp, nullptr, BB * LL, HH, FF, HH);
  // featCtx = features @ W_ih_ctx^T  (bf16, remapped to [64 nt][3136][64])
  tgemm_k<2><<<dim3(25, 32), 256, 0, stream>>>(
      featb, Wctxb, nullptr, featCtx, BB * LL, 4096, FF, 0);

  // ---- timestep loop: 2 dispatches per step ----
  for (int t = 0; t < TT; ++t) {
    const short* hHi = (t == 0) ? h0H : hallH + (size_t)(t - 1) * BB * HH;
    const short* hLi = (t == 0) ? h0L : hallL + (size_t)(t - 1) * BB * HH;
    hupart_k<<<256, 256, 0, stream>>>(
        hHi, hLi, attUt, featp, att_v, partS);
    glstm3_k<<<256, 256, 0, stream>>>(
        xgH, xgL, hHi, hLi, Wxg, Whb, featCtx, partS, bg, cbuf,
        hallH + (size_t)t * BB * HH, hallL + (size_t)t * BB * HH, w_out, t);
  }

  // ---- deferred batched fc ----
  bgemm_k<<<dim3(16, 94), 256, 0, stream>>>(hallH, hallL, fcWb, fc_b, outs);
}